// Round 7
// baseline (171.883 us; speedup 1.0000x reference)
//
#include <hip/hip_runtime.h>
#include <math.h>

#define N2C 16000
#define N1C 4000
#define N0C 1000
#define DEG 32
#define NHEAD 4
#define ALPHA 0.2f
#define LDP 264     // padded LDS row pitch (ushorts): 264*2=528 B, 16B-aligned, 2-way banks

typedef __attribute__((ext_vector_type(8))) short bf16x8;
typedef __attribute__((ext_vector_type(4))) float f32x4;

__device__ __forceinline__ ushort f2bf(float f) {
    unsigned u = __float_as_uint(f);
    unsigned r = (u + 0x7fffu + ((u >> 16) & 1u)) >> 16;   // RTNE
    return (ushort)r;
}
__device__ __forceinline__ float bf2f(ushort h) {
    return __uint_as_float(((unsigned)h) << 16);
}

// ---------------- K0: repack W0 -> bf16 hi/lo [n][k]; fold a1 through W1 -> ahat ----
// Layer-2 score linearization: s_t[h][i] = (x1[i]@Wc1).a1t[h] = x1[i].aht[h],
// aht[h][k] = sum_o W1[h][k][o]*a1[h][o]  (ahn with a1[h][64+o]).
__global__ __launch_bounds__(256) void repack_kernel(
    const float* __restrict__ W0, const float* __restrict__ W1,
    const float* __restrict__ a1,
    ushort* __restrict__ Wth, ushort* __restrict__ Wtl,
    float* __restrict__ aht, float* __restrict__ ahn)
{
    if (blockIdx.x == 256) {   // fold a1 through W1
        int k = threadIdx.x;
#pragma unroll
        for (int h = 0; h < NHEAD; ++h) {
            const float* wrow = W1 + h * 16384 + k * 64;
            const float* av = a1 + h * 128;
            float st = 0.f, sn = 0.f;
#pragma unroll 8
            for (int o = 0; o < 64; ++o) {
                st += wrow[o] * av[o];
                sn += wrow[o] * av[64 + o];
            }
            aht[h * 256 + k] = st;
            ahn[h * 256 + k] = sn;
        }
        return;
    }
    int g = blockIdx.x * 256 + threadIdx.x;   // 0 .. 65535 (W0 only)
    int c = g >> 8, k = g & 255;
    float v = W0[(c >> 6) * (256 * 64) + k * 64 + (c & 63)];
    ushort h = f2bf(v);
    __builtin_nontemporal_store(h, &Wth[g]);
    __builtin_nontemporal_store(f2bf(v - bf2f(h)), &Wtl[g]);
}

// ---------------- K1: h0 = x @ Wc0 (split-bf16 MFMA) + layer-1 scores --------------
// A fp32 staged+converted once per block into LDS hi/lo; 500 blocks x 32 rows.
__global__ __launch_bounds__(256) void gemm1_kernel(
    const float* __restrict__ Af,
    const ushort* __restrict__ Bh, const ushort* __restrict__ Bl,
    const float* __restrict__ avec,
    float* __restrict__ out, float* __restrict__ s_t, float* __restrict__ s_n)
{
    __shared__ ushort sah[32 * LDP];
    __shared__ ushort sal[32 * LDP];
    const int wave = threadIdx.x >> 6, lane = threadIdx.x & 63;
    const int quad = lane >> 4, l16 = lane & 15;
    const int row0 = blockIdx.x * 32;            // 500*32 = 16000 exactly, no clamp
    const int col0 = wave * 64;

    for (int idx = threadIdx.x; idx < 32 * 64; idx += 256) {
        int row = idx >> 6, c4 = idx & 63;
        float4 f = ((const float4*)Af)[(size_t)(row0 + row) * 64 + c4];
        ushort4 h, l;
        h.x = f2bf(f.x); l.x = f2bf(f.x - bf2f(h.x));
        h.y = f2bf(f.y); l.y = f2bf(f.y - bf2f(h.y));
        h.z = f2bf(f.z); l.z = f2bf(f.z - bf2f(h.z));
        h.w = f2bf(f.w); l.w = f2bf(f.w - bf2f(h.w));
        *(ushort4*)(&sah[row * LDP + c4 * 4]) = h;
        *(ushort4*)(&sal[row * LDP + c4 * 4]) = l;
    }
    __syncthreads();

    f32x4 acc[2][4];
#pragma unroll
    for (int r = 0; r < 2; ++r)
#pragma unroll
        for (int c = 0; c < 4; ++c) acc[r][c] = (f32x4){0.f, 0.f, 0.f, 0.f};
    const int kbase = quad * 8;

    for (int k0 = 0; k0 < 256; k0 += 32) {
        bf16x8 a_h[2], a_l[2], b_h[4], b_l[4];
#pragma unroll
        for (int r = 0; r < 2; ++r) {
            int loff = (r * 16 + l16) * LDP + k0 + kbase;
            a_h[r] = *(const bf16x8*)(&sah[loff]);
            a_l[r] = *(const bf16x8*)(&sal[loff]);
        }
#pragma unroll
        for (int c = 0; c < 4; ++c) {
            int off = (col0 + c * 16 + l16) * 256 + k0 + kbase;
            b_h[c] = *(const bf16x8*)(Bh + off);
            b_l[c] = *(const bf16x8*)(Bl + off);
        }
#pragma unroll
        for (int r = 0; r < 2; ++r)
#pragma unroll
            for (int c = 0; c < 4; ++c) {
                acc[r][c] = __builtin_amdgcn_mfma_f32_16x16x32_bf16(a_h[r], b_h[c], acc[r][c], 0, 0, 0);
                acc[r][c] = __builtin_amdgcn_mfma_f32_16x16x32_bf16(a_h[r], b_l[c], acc[r][c], 0, 0, 0);
                acc[r][c] = __builtin_amdgcn_mfma_f32_16x16x32_bf16(a_l[r], b_h[c], acc[r][c], 0, 0, 0);
            }
    }

    // C/D layout: col = lane&15, row = quad*4 + reg  [measured m89/m91]
#pragma unroll
    for (int r = 0; r < 2; ++r)
#pragma unroll
        for (int c = 0; c < 4; ++c) {
            int col = col0 + c * 16 + l16;
#pragma unroll
            for (int reg = 0; reg < 4; ++reg) {
                int row = row0 + r * 16 + quad * 4 + reg;
                __builtin_nontemporal_store(acc[r][c][reg], &out[(size_t)row * 256 + col]);
            }
        }

    // fused layer-1 scores: head == wave
    float at[4], an[4];
#pragma unroll
    for (int c = 0; c < 4; ++c) {
        at[c] = avec[wave * 128 + c * 16 + l16];
        an[c] = avec[wave * 128 + 64 + c * 16 + l16];
    }
#pragma unroll
    for (int r = 0; r < 2; ++r) {
        float pt[4] = {0.f, 0.f, 0.f, 0.f}, pn[4] = {0.f, 0.f, 0.f, 0.f};
#pragma unroll
        for (int c = 0; c < 4; ++c)
#pragma unroll
            for (int reg = 0; reg < 4; ++reg) {
                pt[reg] += acc[r][c][reg] * at[c];
                pn[reg] += acc[r][c][reg] * an[c];
            }
#pragma unroll
        for (int reg = 0; reg < 4; ++reg)
#pragma unroll
            for (int m = 1; m < 16; m <<= 1) {
                pt[reg] += __shfl_xor(pt[reg], m);
                pn[reg] += __shfl_xor(pn[reg], m);
            }
        if (l16 == 0) {
#pragma unroll
            for (int reg = 0; reg < 4; ++reg) {
                int row = row0 + r * 16 + quad * 4 + reg;
                __builtin_nontemporal_store(pt[reg], &s_t[wave * N2C + row]);
                __builtin_nontemporal_store(pn[reg], &s_n[wave * N2C + row]);
            }
        }
    }
}

// ---------------- K2: att1 — one target/block; fp32 x1 out + fused layer-2 scores ---
__global__ __launch_bounds__(256) void att1_kernel(
    const float* __restrict__ hprev, const int* __restrict__ nbr_arr,
    const float* __restrict__ s_t, const float* __restrict__ s_n,
    const float* __restrict__ aht, const float* __restrict__ ahn,
    float* __restrict__ x1, float* __restrict__ st2, float* __restrict__ sn2)
{
    __shared__ int nbr[DEG + 1];
    __shared__ float att_s[NHEAD][DEG + 3];
    __shared__ float4 red[4][64];
    const int tgt = blockIdx.x;
    const int t = threadIdx.x;
    const int lane = t & 63;
    if (t < DEG) nbr[t] = nbr_arr[tgt * DEG + t];
    else if (t == DEG) nbr[DEG] = nbr_arr[N1C * DEG + tgt];  // self-loop edge
    __syncthreads();

    {   // wave = head; lane = edge index (33 edges), lanes 33..63 inert
        const int hd = t >> 6;
        int me = (lane <= DEG) ? nbr[lane] : -1;
        int k = (lane <= DEG) ? 1 : 0;
#pragma unroll
        for (int j = 0; j < DEG; ++j) {          // dedupe scan via shuffle
            int v = __shfl(me, j);
            if (j < lane && v == me) k = 0;
        }
        float e = s_t[hd * N2C + tgt] + ((lane <= DEG) ? s_n[hd * N2C + me] : 0.f);
        e = (e >= 0.f) ? e : ALPHA * e;          // LeakyReLU(0.2)
        float em = k ? e : -1e30f;
        float m = em;
#pragma unroll
        for (int off = 1; off < 64; off <<= 1) m = fmaxf(m, __shfl_xor(m, off));
        float w = k ? __expf(e - m) : 0.f;
        float Z = w;
#pragma unroll
        for (int off = 1; off < 64; off <<= 1) Z += __shfl_xor(Z, off);
        if (lane <= DEG) att_s[hd][lane] = w / Z;
    }
    __syncthreads();

    // aggregation: thread = (rg = t>>6 row-group, cq = t&63 channel-quad)
    const int cq = t & 63;
    const int rg = t >> 6;
    const int hd = cq >> 4;
    const float4* hp4 = (const float4*)hprev;
    float4 acc = make_float4(0.f, 0.f, 0.f, 0.f);
#pragma unroll
    for (int ii = 0; ii < 9; ++ii) {
        int i = rg + ii * 4;
        if (i <= DEG) {
            float w = att_s[hd][i];                       // dup edges: w==0
            float4 v = hp4[(size_t)nbr[i] * 64 + cq];
            acc.x += w * v.x; acc.y += w * v.y;
            acc.z += w * v.z; acc.w += w * v.w;
        }
    }
    red[rg][cq] = acc;
    __syncthreads();
    if (t < 64) {
        float4 s0 = red[0][t], s1 = red[1][t], s2 = red[2][t], s3 = red[3][t];
        float4 s;
        s.x = s0.x + s1.x + s2.x + s3.x;
        s.y = s0.y + s1.y + s2.y + s3.y;
        s.z = s0.z + s1.z + s2.z + s3.z;
        s.w = s0.w + s1.w + s2.w + s3.w;
        s.x = (s.x > 0.f) ? s.x : expm1f(s.x);   // ELU
        s.y = (s.y > 0.f) ? s.y : expm1f(s.y);
        s.z = (s.z > 0.f) ? s.z : expm1f(s.z);
        s.w = (s.w > 0.f) ? s.w : expm1f(s.w);
        f32x4 v4 = (f32x4){s.x, s.y, s.z, s.w};
        __builtin_nontemporal_store(v4, &((f32x4*)x1)[tgt * 64 + t]);

        // fused layer-2 scores via linearized a-fold: st2[h] = x1[tgt].aht[h]
        float pt[NHEAD], pn[NHEAD];
#pragma unroll
        for (int h = 0; h < NHEAD; ++h) {
            float4 a4 = ((const float4*)aht)[h * 64 + t];
            float4 b4 = ((const float4*)ahn)[h * 64 + t];
            pt[h] = s.x * a4.x + s.y * a4.y + s.z * a4.z + s.w * a4.w;
            pn[h] = s.x * b4.x + s.y * b4.y + s.z * b4.z + s.w * b4.w;
        }
#pragma unroll
        for (int h = 0; h < NHEAD; ++h)
#pragma unroll
            for (int off = 1; off < 64; off <<= 1) {
                pt[h] += __shfl_xor(pt[h], off);
                pn[h] += __shfl_xor(pn[h], off);
            }
        if (t == 0) {
#pragma unroll
            for (int h = 0; h < NHEAD; ++h) {
                st2[h * N1C + tgt] = pt[h];
                sn2[h * N1C + tgt] = pn[h];
            }
        }
    }
}

// ---------------- K3: att2 (aggregate x1) -> @Wc1 -> ELU -> Linear -> Tanh ----------
// Linearity: sum_e w_e*(x1[e]@Wc1) = (sum_e w_e*x1[e])@Wc1 — gemm2 eliminated.
// 250 blocks x 4 targets; wave = target for softmax+gather, then 256-thread matvecs.
__global__ __launch_bounds__(256) void att2_lin_kernel(
    const float* __restrict__ x1, const int* __restrict__ nbr_arr,
    const float* __restrict__ s_t, const float* __restrict__ s_n,
    const float* __restrict__ W1, const float* __restrict__ linW,
    const float* __restrict__ bias, float* __restrict__ out)
{
    __shared__ int   nbr_s[4][DEG + 1];
    __shared__ float att_w[4][NHEAD][DEG + 1];
    __shared__ float yb[4][256];
    __shared__ float x2[4][256];

    const int wave = threadIdx.x >> 6, lane = threadIdx.x & 63;
    const int blk = blockIdx.x;                  // 250 blocks * 4 targets = 1000

    for (int idx = threadIdx.x; idx < 4 * (DEG + 1); idx += 256) {
        int tt = idx / (DEG + 1), e = idx - tt * (DEG + 1);
        nbr_s[tt][e] = (e < DEG) ? nbr_arr[(blk * 4 + tt) * DEG + e]
                                 : nbr_arr[N0C * DEG + blk * 4 + tt];
    }
    __syncthreads();

    {   // softmax: wave = target, lane = edge
        const int tl = wave;
        const int gt = blk * 4 + tl;
        int me = (lane <= DEG) ? nbr_s[tl][lane] : 0;
        int k = (lane <= DEG) ? 1 : 0;
#pragma unroll
        for (int j = 0; j < DEG; ++j) {
            int v = __shfl(me, j);
            if (j < lane && v == me) k = 0;
        }
#pragma unroll
        for (int hd = 0; hd < NHEAD; ++hd) {
            float e = s_t[hd * N1C + gt] + s_n[hd * N1C + me];
            e = (e >= 0.f) ? e : ALPHA * e;
            float em = k ? e : -1e30f;
            float m = em;
#pragma unroll
            for (int off = 1; off < 64; off <<= 1) m = fmaxf(m, __shfl_xor(m, off));
            float w = k ? __expf(e - m) : 0.f;
            float Z = w;
#pragma unroll
            for (int off = 1; off < 64; off <<= 1) Z += __shfl_xor(Z, off);
            if (lane <= DEG) att_w[tl][hd][lane] = w / Z;
        }
    }
    __syncthreads();
    {   // y = sum_e w_e * x1[nbr_e]  (pre-matmul aggregate; NO ELU here)
        const int tl = wave;
        const int hh = lane >> 4;
        float4 acc = make_float4(0.f, 0.f, 0.f, 0.f);
#pragma unroll
        for (int e = 0; e <= DEG; ++e) {
            float w = att_w[tl][hh][e];
            float4 v = ((const float4*)x1)[(size_t)nbr_s[tl][e] * 64 + lane];
            acc.x += w * v.x; acc.y += w * v.y;
            acc.z += w * v.z; acc.w += w * v.w;
        }
        *(float4*)(&yb[tl][lane * 4]) = acc;
    }
    __syncthreads();

    // z = y @ Wc1 (per-target matvec), then ELU -> x2. Wc1[k][64h+o] = W1[h][k][o].
    {
        const int c = threadIdx.x;
        const float* wcol = W1 + (c >> 6) * 16384 + (c & 63);
        float z0 = 0.f, z1 = 0.f, z2 = 0.f, z3 = 0.f;
#pragma unroll 4
        for (int k = 0; k < 256; ++k) {
            float wv = wcol[k * 64];             // coalesced across threads at fixed k
            z0 += yb[0][k] * wv; z1 += yb[1][k] * wv;
            z2 += yb[2][k] * wv; z3 += yb[3][k] * wv;
        }
        x2[0][c] = (z0 > 0.f) ? z0 : expm1f(z0);
        x2[1][c] = (z1 > 0.f) ? z1 : expm1f(z1);
        x2[2][c] = (z2 > 0.f) ? z2 : expm1f(z2);
        x2[3][c] = (z3 > 0.f) ? z3 : expm1f(z3);
    }
    __syncthreads();

    // final linear: thread = output channel c; fp32 matvec over linW row [c][0..255]
    const int c = threadIdx.x;
    const float4* wrow = (const float4*)(linW + c * 256);
    float v0 = 0.f, v1 = 0.f, v2 = 0.f, v3 = 0.f;
    for (int q = 0; q < 64; ++q) {
        float4 wv = wrow[q];
        int kk = q * 4;
        v0 += x2[0][kk] * wv.x + x2[0][kk+1] * wv.y + x2[0][kk+2] * wv.z + x2[0][kk+3] * wv.w;
        v1 += x2[1][kk] * wv.x + x2[1][kk+1] * wv.y + x2[1][kk+2] * wv.z + x2[1][kk+3] * wv.w;
        v2 += x2[2][kk] * wv.x + x2[2][kk+1] * wv.y + x2[2][kk+2] * wv.z + x2[2][kk+3] * wv.w;
        v3 += x2[3][kk] * wv.x + x2[3][kk+1] * wv.y + x2[3][kk+2] * wv.z + x2[3][kk+3] * wv.w;
    }
    float b = bias[c];
    out[(size_t)(blk * 4 + 0) * 256 + c] = tanhf(v0 + b);
    out[(size_t)(blk * 4 + 1) * 256 + c] = tanhf(v1 + b);
    out[(size_t)(blk * 4 + 2) * 256 + c] = tanhf(v2 + b);
    out[(size_t)(blk * 4 + 3) * 256 + c] = tanhf(v3 + b);
}

extern "C" void kernel_launch(void* const* d_in, const int* in_sizes, int n_in,
                              void* d_out, int out_size, void* d_ws, size_t ws_size,
                              hipStream_t stream)
{
    const float* x    = (const float*)d_in[0];
    const float* W0   = (const float*)d_in[1];
    const float* a0   = (const float*)d_in[2];
    const float* W1   = (const float*)d_in[3];
    const float* a1   = (const float*)d_in[4];
    const float* linW = (const float*)d_in[5];
    const float* linb = (const float*)d_in[6];
    const int* adj1_nbr = (const int*)d_in[8];
    const int* adj0_nbr = (const int*)d_in[10];

    char* base = (char*)d_ws;
    ushort* Wth = (ushort*)base;                 // 65536 ushort = 128 KB (W0 only)
    ushort* Wtl = (ushort*)(base + 131072);      // 128 KB          (ends 262144)
    float*  aht = (float*)(base + 262144);       // 4x256 f32 = 4 KB
    float*  ahn = (float*)(base + 266240);       // 4 KB            (ends 270336)
    float*  st  = (float*)(base + 524288);       // 4x16000 f32 (256 KB slot)
    float*  sn  = (float*)(base + 786432);       //                 (ends 1048576)
    float*  st2 = (float*)(base + 1048576);      // 4x4000 f32 (64 KB slot)
    float*  sn2 = (float*)(base + 1114112);      //                 (ends 1179648)
    float*  x1  = (float*)(base + 1179648);      // 4000*256 f32 = 4 MB (ends 5373952)
    float*  h0  = (float*)(base + 5373952);      // 16000*256 f32 = 16 MB (ends ~22.2 MB)

    // K0: W0 repack (bf16 hi/lo, [n][k]) + a1-through-W1 fold (block 256)
    repack_kernel<<<257, 256, 0, stream>>>(W0, W1, a1, Wth, Wtl, aht, ahn);

    // K1: h0 = x @ Wc0 + layer-1 scores
    gemm1_kernel<<<N2C / 32, 256, 0, stream>>>(x, Wth, Wtl, a0, h0, st, sn);

    // K2: att1 (4000 blocks) -> x1 fp32 + fused layer-2 scores (linearized)
    att1_kernel<<<N1C, 256, 0, stream>>>(h0, adj1_nbr, st, sn, aht, ahn, x1, st2, sn2);

    // K3: att2 aggregate -> @Wc1 -> ELU -> Linear+Tanh  (gemm2 eliminated by linearity)
    att2_lin_kernel<<<N0C / 4, 256, 0, stream>>>(
        x1, adj0_nbr, st2, sn2, W1, linW, linb, (float*)d_out);
}

// Round 8
// 168.423 us; speedup vs baseline: 1.0205x; 1.0205x over previous
//
#include <hip/hip_runtime.h>
#include <math.h>

#define N2C 16000
#define N1C 4000
#define N0C 1000
#define DEG 32
#define NHEAD 4
#define ALPHA 0.2f
#define LDP 264     // padded LDS row pitch (ushorts): 264*2=528 B, 16B-aligned, 2-way banks

typedef __attribute__((ext_vector_type(8))) short bf16x8;
typedef __attribute__((ext_vector_type(4))) float f32x4;

__device__ __forceinline__ ushort f2bf(float f) {
    unsigned u = __float_as_uint(f);
    unsigned r = (u + 0x7fffu + ((u >> 16) & 1u)) >> 16;   // RTNE
    return (ushort)r;
}
__device__ __forceinline__ float bf2f(ushort h) {
    return __uint_as_float(((unsigned)h) << 16);
}

// ---------------- K0: W0 -> bf16 hi/lo [n][k]; a1 fold; linW transpose --------------
// blocks 0-255: W0 repack. blocks 256-511: linWT[k][c] = linW[c][k] (fp32).
// block 512: aht[h][k] = sum_o W1[h][k][o]*a1[h][o] (ahn with a1[h][64+o]).
__global__ __launch_bounds__(256) void repack_kernel(
    const float* __restrict__ W0, const float* __restrict__ W1,
    const float* __restrict__ a1, const float* __restrict__ linW,
    ushort* __restrict__ Wth, ushort* __restrict__ Wtl,
    float* __restrict__ aht, float* __restrict__ ahn, float* __restrict__ linWT)
{
    const int b = blockIdx.x;
    if (b == 512) {   // fold a1 through W1
        int k = threadIdx.x;
#pragma unroll
        for (int h = 0; h < NHEAD; ++h) {
            const float* wrow = W1 + h * 16384 + k * 64;
            const float* av = a1 + h * 128;
            float st = 0.f, sn = 0.f;
#pragma unroll 8
            for (int o = 0; o < 64; ++o) {
                st += wrow[o] * av[o];
                sn += wrow[o] * av[64 + o];
            }
            aht[h * 256 + k] = st;
            ahn[h * 256 + k] = sn;
        }
        return;
    }
    if (b >= 256) {   // linW transpose (fp32): coalesced NT writes
        int idx = (b - 256) * 256 + threadIdx.x;   // 0..65535
        int k = idx >> 8, c = idx & 255;
        __builtin_nontemporal_store(linW[c * 256 + k], &linWT[k * 256 + c]);
        return;
    }
    int g = b * 256 + threadIdx.x;   // 0 .. 65535 (W0 only)
    int c = g >> 8, k = g & 255;
    float v = W0[(c >> 6) * (256 * 64) + k * 64 + (c & 63)];
    ushort h = f2bf(v);
    __builtin_nontemporal_store(h, &Wth[g]);
    __builtin_nontemporal_store(f2bf(v - bf2f(h)), &Wtl[g]);
}

// ---------------- K1: h0 = x @ Wc0 (split-bf16 MFMA) + layer-1 scores --------------
// A fp32 staged+converted once per block into LDS hi/lo; 500 blocks x 32 rows.
__global__ __launch_bounds__(256) void gemm1_kernel(
    const float* __restrict__ Af,
    const ushort* __restrict__ Bh, const ushort* __restrict__ Bl,
    const float* __restrict__ avec,
    float* __restrict__ out, float* __restrict__ s_t, float* __restrict__ s_n)
{
    __shared__ ushort sah[32 * LDP];
    __shared__ ushort sal[32 * LDP];
    const int wave = threadIdx.x >> 6, lane = threadIdx.x & 63;
    const int quad = lane >> 4, l16 = lane & 15;
    const int row0 = blockIdx.x * 32;            // 500*32 = 16000 exactly, no clamp
    const int col0 = wave * 64;

    for (int idx = threadIdx.x; idx < 32 * 64; idx += 256) {
        int row = idx >> 6, c4 = idx & 63;
        float4 f = ((const float4*)Af)[(size_t)(row0 + row) * 64 + c4];
        ushort4 h, l;
        h.x = f2bf(f.x); l.x = f2bf(f.x - bf2f(h.x));
        h.y = f2bf(f.y); l.y = f2bf(f.y - bf2f(h.y));
        h.z = f2bf(f.z); l.z = f2bf(f.z - bf2f(h.z));
        h.w = f2bf(f.w); l.w = f2bf(f.w - bf2f(h.w));
        *(ushort4*)(&sah[row * LDP + c4 * 4]) = h;
        *(ushort4*)(&sal[row * LDP + c4 * 4]) = l;
    }
    __syncthreads();

    f32x4 acc[2][4];
#pragma unroll
    for (int r = 0; r < 2; ++r)
#pragma unroll
        for (int c = 0; c < 4; ++c) acc[r][c] = (f32x4){0.f, 0.f, 0.f, 0.f};
    const int kbase = quad * 8;

    for (int k0 = 0; k0 < 256; k0 += 32) {
        bf16x8 a_h[2], a_l[2], b_h[4], b_l[4];
#pragma unroll
        for (int r = 0; r < 2; ++r) {
            int loff = (r * 16 + l16) * LDP + k0 + kbase;
            a_h[r] = *(const bf16x8*)(&sah[loff]);
            a_l[r] = *(const bf16x8*)(&sal[loff]);
        }
#pragma unroll
        for (int c = 0; c < 4; ++c) {
            int off = (col0 + c * 16 + l16) * 256 + k0 + kbase;
            b_h[c] = *(const bf16x8*)(Bh + off);
            b_l[c] = *(const bf16x8*)(Bl + off);
        }
#pragma unroll
        for (int r = 0; r < 2; ++r)
#pragma unroll
            for (int c = 0; c < 4; ++c) {
                acc[r][c] = __builtin_amdgcn_mfma_f32_16x16x32_bf16(a_h[r], b_h[c], acc[r][c], 0, 0, 0);
                acc[r][c] = __builtin_amdgcn_mfma_f32_16x16x32_bf16(a_h[r], b_l[c], acc[r][c], 0, 0, 0);
                acc[r][c] = __builtin_amdgcn_mfma_f32_16x16x32_bf16(a_l[r], b_h[c], acc[r][c], 0, 0, 0);
            }
    }

    // C/D layout: col = lane&15, row = quad*4 + reg  [measured m89/m91]
#pragma unroll
    for (int r = 0; r < 2; ++r)
#pragma unroll
        for (int c = 0; c < 4; ++c) {
            int col = col0 + c * 16 + l16;
#pragma unroll
            for (int reg = 0; reg < 4; ++reg) {
                int row = row0 + r * 16 + quad * 4 + reg;
                __builtin_nontemporal_store(acc[r][c][reg], &out[(size_t)row * 256 + col]);
            }
        }

    // fused layer-1 scores: head == wave
    float at[4], an[4];
#pragma unroll
    for (int c = 0; c < 4; ++c) {
        at[c] = avec[wave * 128 + c * 16 + l16];
        an[c] = avec[wave * 128 + 64 + c * 16 + l16];
    }
#pragma unroll
    for (int r = 0; r < 2; ++r) {
        float pt[4] = {0.f, 0.f, 0.f, 0.f}, pn[4] = {0.f, 0.f, 0.f, 0.f};
#pragma unroll
        for (int c = 0; c < 4; ++c)
#pragma unroll
            for (int reg = 0; reg < 4; ++reg) {
                pt[reg] += acc[r][c][reg] * at[c];
                pn[reg] += acc[r][c][reg] * an[c];
            }
#pragma unroll
        for (int reg = 0; reg < 4; ++reg)
#pragma unroll
            for (int m = 1; m < 16; m <<= 1) {
                pt[reg] += __shfl_xor(pt[reg], m);
                pn[reg] += __shfl_xor(pn[reg], m);
            }
        if (l16 == 0) {
#pragma unroll
            for (int reg = 0; reg < 4; ++reg) {
                int row = row0 + r * 16 + quad * 4 + reg;
                __builtin_nontemporal_store(pt[reg], &s_t[wave * N2C + row]);
                __builtin_nontemporal_store(pn[reg], &s_n[wave * N2C + row]);
            }
        }
    }
}

// ---------------- K2: att1 — one target/block; fp32 x1 out + fused layer-2 scores ---
__global__ __launch_bounds__(256) void att1_kernel(
    const float* __restrict__ hprev, const int* __restrict__ nbr_arr,
    const float* __restrict__ s_t, const float* __restrict__ s_n,
    const float* __restrict__ aht, const float* __restrict__ ahn,
    float* __restrict__ x1, float* __restrict__ st2, float* __restrict__ sn2)
{
    __shared__ int nbr[DEG + 1];
    __shared__ float att_s[NHEAD][DEG + 3];
    __shared__ float4 red[4][64];
    const int tgt = blockIdx.x;
    const int t = threadIdx.x;
    const int lane = t & 63;
    if (t < DEG) nbr[t] = nbr_arr[tgt * DEG + t];
    else if (t == DEG) nbr[DEG] = nbr_arr[N1C * DEG + tgt];  // self-loop edge
    __syncthreads();

    {   // wave = head; lane = edge index (33 edges), lanes 33..63 inert
        const int hd = t >> 6;
        int me = (lane <= DEG) ? nbr[lane] : -1;
        int k = (lane <= DEG) ? 1 : 0;
#pragma unroll
        for (int j = 0; j < DEG; ++j) {          // dedupe scan via shuffle
            int v = __shfl(me, j);
            if (j < lane && v == me) k = 0;
        }
        float e = s_t[hd * N2C + tgt] + ((lane <= DEG) ? s_n[hd * N2C + me] : 0.f);
        e = (e >= 0.f) ? e : ALPHA * e;          // LeakyReLU(0.2)
        float em = k ? e : -1e30f;
        float m = em;
#pragma unroll
        for (int off = 1; off < 64; off <<= 1) m = fmaxf(m, __shfl_xor(m, off));
        float w = k ? __expf(e - m) : 0.f;
        float Z = w;
#pragma unroll
        for (int off = 1; off < 64; off <<= 1) Z += __shfl_xor(Z, off);
        if (lane <= DEG) att_s[hd][lane] = w / Z;
    }
    __syncthreads();

    // aggregation: thread = (rg = t>>6 row-group, cq = t&63 channel-quad)
    const int cq = t & 63;
    const int rg = t >> 6;
    const int hd = cq >> 4;
    const float4* hp4 = (const float4*)hprev;
    float4 acc = make_float4(0.f, 0.f, 0.f, 0.f);
#pragma unroll
    for (int ii = 0; ii < 9; ++ii) {
        int i = rg + ii * 4;
        if (i <= DEG) {
            float w = att_s[hd][i];                       // dup edges: w==0
            float4 v = hp4[(size_t)nbr[i] * 64 + cq];
            acc.x += w * v.x; acc.y += w * v.y;
            acc.z += w * v.z; acc.w += w * v.w;
        }
    }
    red[rg][cq] = acc;
    __syncthreads();
    if (t < 64) {
        float4 s0 = red[0][t], s1 = red[1][t], s2 = red[2][t], s3 = red[3][t];
        float4 s;
        s.x = s0.x + s1.x + s2.x + s3.x;
        s.y = s0.y + s1.y + s2.y + s3.y;
        s.z = s0.z + s1.z + s2.z + s3.z;
        s.w = s0.w + s1.w + s2.w + s3.w;
        s.x = (s.x > 0.f) ? s.x : expm1f(s.x);   // ELU
        s.y = (s.y > 0.f) ? s.y : expm1f(s.y);
        s.z = (s.z > 0.f) ? s.z : expm1f(s.z);
        s.w = (s.w > 0.f) ? s.w : expm1f(s.w);
        f32x4 v4 = (f32x4){s.x, s.y, s.z, s.w};
        __builtin_nontemporal_store(v4, &((f32x4*)x1)[tgt * 64 + t]);

        // fused layer-2 scores via linearized a-fold: st2[h] = x1[tgt].aht[h]
        float pt[NHEAD], pn[NHEAD];
#pragma unroll
        for (int h = 0; h < NHEAD; ++h) {
            float4 a4 = ((const float4*)aht)[h * 64 + t];
            float4 b4 = ((const float4*)ahn)[h * 64 + t];
            pt[h] = s.x * a4.x + s.y * a4.y + s.z * a4.z + s.w * a4.w;
            pn[h] = s.x * b4.x + s.y * b4.y + s.z * b4.z + s.w * b4.w;
        }
#pragma unroll
        for (int h = 0; h < NHEAD; ++h)
#pragma unroll
            for (int off = 1; off < 64; off <<= 1) {
                pt[h] += __shfl_xor(pt[h], off);
                pn[h] += __shfl_xor(pn[h], off);
            }
        if (t == 0) {
#pragma unroll
            for (int h = 0; h < NHEAD; ++h) {
                st2[h * N1C + tgt] = pt[h];
                sn2[h * N1C + tgt] = pn[h];
            }
        }
    }
}

// ---------------- K3: att2 (aggregate x1) -> @Wc1 -> ELU -> Linear -> Tanh ----------
// ONE target per block (1000 blocks) — round-7 lesson: 250 blocks = 1/CU = latency-
// bound serial phases (43.8us @ 9.5% occupancy). Linearity still eliminates gemm2.
__global__ __launch_bounds__(256) void att2_lin_kernel(
    const float* __restrict__ x1, const int* __restrict__ nbr_arr,
    const float* __restrict__ s_t, const float* __restrict__ s_n,
    const float* __restrict__ W1, const float* __restrict__ linWT,
    const float* __restrict__ bias, float* __restrict__ out)
{
    __shared__ int nbr[DEG + 1];
    __shared__ float att_s[NHEAD][DEG + 3];
    __shared__ float4 red[4][64];
    __shared__ float yb[256];
    __shared__ float x2[256];
    const int tgt = blockIdx.x;
    const int t = threadIdx.x;
    const int lane = t & 63;
    if (t < DEG) nbr[t] = nbr_arr[tgt * DEG + t];
    else if (t == DEG) nbr[DEG] = nbr_arr[N0C * DEG + tgt];  // self-loop edge
    __syncthreads();

    {   // softmax: wave = head, lane = edge
        const int hd = t >> 6;
        int me = (lane <= DEG) ? nbr[lane] : -1;
        int k = (lane <= DEG) ? 1 : 0;
#pragma unroll
        for (int j = 0; j < DEG; ++j) {
            int v = __shfl(me, j);
            if (j < lane && v == me) k = 0;
        }
        float e = s_t[hd * N1C + tgt] + ((lane <= DEG) ? s_n[hd * N1C + me] : 0.f);
        e = (e >= 0.f) ? e : ALPHA * e;
        float em = k ? e : -1e30f;
        float m = em;
#pragma unroll
        for (int off = 1; off < 64; off <<= 1) m = fmaxf(m, __shfl_xor(m, off));
        float w = k ? __expf(e - m) : 0.f;
        float Z = w;
#pragma unroll
        for (int off = 1; off < 64; off <<= 1) Z += __shfl_xor(Z, off);
        if (lane <= DEG) att_s[hd][lane] = w / Z;
    }
    __syncthreads();

    // y = sum_e w_e * x1[nbr_e]  (pre-matmul aggregate; NO ELU here)
    {
        const int cq = t & 63;
        const int rg = t >> 6;
        const int hd = cq >> 4;
        float4 acc = make_float4(0.f, 0.f, 0.f, 0.f);
#pragma unroll
        for (int ii = 0; ii < 9; ++ii) {
            int i = rg + ii * 4;
            if (i <= DEG) {
                float w = att_s[hd][i];
                float4 v = ((const float4*)x1)[(size_t)nbr[i] * 64 + cq];
                acc.x += w * v.x; acc.y += w * v.y;
                acc.z += w * v.z; acc.w += w * v.w;
            }
        }
        red[rg][cq] = acc;
    }
    __syncthreads();
    if (t < 64) {
        float4 s0 = red[0][t], s1 = red[1][t], s2 = red[2][t], s3 = red[3][t];
        yb[t * 4 + 0] = s0.x + s1.x + s2.x + s3.x;
        yb[t * 4 + 1] = s0.y + s1.y + s2.y + s3.y;
        yb[t * 4 + 2] = s0.z + s1.z + s2.z + s3.z;
        yb[t * 4 + 3] = s0.w + s1.w + s2.w + s3.w;
    }
    __syncthreads();

    // z = y @ Wc1 (thread = out channel), ELU -> x2.  Wc1[k][64h+o] = W1[h][k][o];
    // at fixed k, threads of a wave read 256B contiguous (one h-segment) — coalesced.
    {
        const float* wcol = W1 + (t >> 6) * 16384 + (t & 63);
        float z = 0.f;
#pragma unroll 8
        for (int k = 0; k < 256; ++k) z += yb[k] * wcol[k * 64];
        x2[t] = (z > 0.f) ? z : expm1f(z);
    }
    __syncthreads();

    // out = tanh(x2 @ linW^T + b) via transposed linWT — coalesced at fixed k
    {
        float v = 0.f;
#pragma unroll 8
        for (int k = 0; k < 256; ++k) v += x2[k] * linWT[k * 256 + t];
        out[(size_t)tgt * 256 + t] = tanhf(v + bias[t]);
    }
}

extern "C" void kernel_launch(void* const* d_in, const int* in_sizes, int n_in,
                              void* d_out, int out_size, void* d_ws, size_t ws_size,
                              hipStream_t stream)
{
    const float* x    = (const float*)d_in[0];
    const float* W0   = (const float*)d_in[1];
    const float* a0   = (const float*)d_in[2];
    const float* W1   = (const float*)d_in[3];
    const float* a1   = (const float*)d_in[4];
    const float* linW = (const float*)d_in[5];
    const float* linb = (const float*)d_in[6];
    const int* adj1_nbr = (const int*)d_in[8];
    const int* adj0_nbr = (const int*)d_in[10];

    char* base = (char*)d_ws;
    ushort* Wth = (ushort*)base;                 // 65536 ushort = 128 KB (W0 only)
    ushort* Wtl = (ushort*)(base + 131072);      // 128 KB          (ends 262144)
    float*  aht = (float*)(base + 262144);       // 4x256 f32 = 4 KB
    float*  ahn = (float*)(base + 266240);       // 4 KB            (ends 270336)
    float*  linWT = (float*)(base + 270336);     // 256x256 f32 = 256 KB (ends 532480)
    float*  st  = (float*)(base + 532480);       // 4x16000 f32 = 256 KB
    float*  sn  = (float*)(base + 794624);       //                 (ends 1056768)
    float*  st2 = (float*)(base + 1056768);      // 4x4000 f32 = 64 KB
    float*  sn2 = (float*)(base + 1122304);      //                 (ends 1187840)
    float*  x1  = (float*)(base + 1187840);      // 4000*256 f32 = 4 MB (ends 5382144)
    float*  h0  = (float*)(base + 5382144);      // 16000*256 f32 = 16 MB (ends ~22.2 MB)

    // K0: W0 repack + linW transpose + a1-through-W1 fold
    repack_kernel<<<513, 256, 0, stream>>>(W0, W1, a1, linW, Wth, Wtl, aht, ahn, linWT);

    // K1: h0 = x @ Wc0 + layer-1 scores
    gemm1_kernel<<<N2C / 32, 256, 0, stream>>>(x, Wth, Wtl, a0, h0, st, sn);

    // K2: att1 (4000 blocks) -> x1 fp32 + fused layer-2 scores (linearized)
    att1_kernel<<<N1C, 256, 0, stream>>>(h0, adj1_nbr, st, sn, aht, ahn, x1, st2, sn2);

    // K3: att2 aggregate -> @Wc1 -> ELU -> Linear+Tanh  (1000 blocks, 1 target each)
    att2_lin_kernel<<<N0C, 256, 0, stream>>>(
        x1, adj0_nbr, st2, sn2, W1, linWT, linb, (float*)d_out);
}

// Round 9
// 166.652 us; speedup vs baseline: 1.0314x; 1.0106x over previous
//
#include <hip/hip_runtime.h>
#include <math.h>

#define N2C 16000
#define N1C 4000
#define N0C 1000
#define DEG 32
#define NHEAD 4
#define ALPHA 0.2f
#define LDP 264     // padded LDS row pitch (ushorts): 264*2=528 B, 16B-aligned, 2-way banks

typedef __attribute__((ext_vector_type(8))) short bf16x8;
typedef __attribute__((ext_vector_type(4))) float f32x4;

__device__ __forceinline__ ushort f2bf(float f) {
    unsigned u = __float_as_uint(f);
    unsigned r = (u + 0x7fffu + ((u >> 16) & 1u)) >> 16;   // RTNE
    return (ushort)r;
}
__device__ __forceinline__ float bf2f(ushort h) {
    return __uint_as_float(((unsigned)h) << 16);
}
__device__ __forceinline__ unsigned long long pack4(ushort a, ushort b, ushort c, ushort d) {
    return (unsigned long long)a | ((unsigned long long)b << 16) |
           ((unsigned long long)c << 32) | ((unsigned long long)d << 48);
}

// ---------------- K0: repack W0,W1 -> bf16 hi/lo [n][k]; transpose linW (fp32) ------
// blocks 0-511: W0,W1 repack. blocks 512-767: linWT[k][c] = linW[c][k].
__global__ __launch_bounds__(256) void repack_kernel(
    const float* __restrict__ W0, const float* __restrict__ W1,
    const float* __restrict__ linW,
    ushort* __restrict__ Wth, ushort* __restrict__ Wtl, float* __restrict__ linWT)
{
    const int b = blockIdx.x;
    if (b >= 512) {   // linW transpose (fp32): coalesced NT writes
        int idx = (b - 512) * 256 + threadIdx.x;   // 0..65535
        int k = idx >> 8, c = idx & 255;
        __builtin_nontemporal_store(linW[c * 256 + k], &linWT[k * 256 + c]);
        return;
    }
    int g = b * 256 + threadIdx.x;   // 0 .. 2*65536-1
    int mat = g >> 16;
    int idx = g & 65535;
    int c = idx >> 8, k = idx & 255;
    const float* W = mat ? W1 : W0;
    float v = W[(c >> 6) * (256 * 64) + k * 64 + (c & 63)];
    ushort h = f2bf(v);
    __builtin_nontemporal_store(h, &Wth[g]);                     // no dirty-L2 buildup
    __builtin_nontemporal_store(f2bf(v - bf2f(h)), &Wtl[g]);
}

// ---------------- K1: h0 = x @ Wc0 (split-bf16 MFMA) + layer-1 scores --------------
// A fp32 staged+converted once per block into LDS hi/lo; 500 blocks x 32 rows.
__global__ __launch_bounds__(256) void gemm1_kernel(
    const float* __restrict__ Af,
    const ushort* __restrict__ Bh, const ushort* __restrict__ Bl,
    const float* __restrict__ avec,
    float* __restrict__ out, float* __restrict__ s_t, float* __restrict__ s_n)
{
    __shared__ ushort sah[32 * LDP];
    __shared__ ushort sal[32 * LDP];
    const int wave = threadIdx.x >> 6, lane = threadIdx.x & 63;
    const int quad = lane >> 4, l16 = lane & 15;
    const int row0 = blockIdx.x * 32;            // 500*32 = 16000 exactly, no clamp
    const int col0 = wave * 64;

    for (int idx = threadIdx.x; idx < 32 * 64; idx += 256) {
        int row = idx >> 6, c4 = idx & 63;
        float4 f = ((const float4*)Af)[(size_t)(row0 + row) * 64 + c4];
        ushort4 h, l;
        h.x = f2bf(f.x); l.x = f2bf(f.x - bf2f(h.x));
        h.y = f2bf(f.y); l.y = f2bf(f.y - bf2f(h.y));
        h.z = f2bf(f.z); l.z = f2bf(f.z - bf2f(h.z));
        h.w = f2bf(f.w); l.w = f2bf(f.w - bf2f(h.w));
        *(ushort4*)(&sah[row * LDP + c4 * 4]) = h;
        *(ushort4*)(&sal[row * LDP + c4 * 4]) = l;
    }
    __syncthreads();

    f32x4 acc[2][4];
#pragma unroll
    for (int r = 0; r < 2; ++r)
#pragma unroll
        for (int c = 0; c < 4; ++c) acc[r][c] = (f32x4){0.f, 0.f, 0.f, 0.f};
    const int kbase = quad * 8;

    for (int k0 = 0; k0 < 256; k0 += 32) {
        bf16x8 a_h[2], a_l[2], b_h[4], b_l[4];
#pragma unroll
        for (int r = 0; r < 2; ++r) {
            int loff = (r * 16 + l16) * LDP + k0 + kbase;
            a_h[r] = *(const bf16x8*)(&sah[loff]);
            a_l[r] = *(const bf16x8*)(&sal[loff]);
        }
#pragma unroll
        for (int c = 0; c < 4; ++c) {
            int off = (col0 + c * 16 + l16) * 256 + k0 + kbase;
            b_h[c] = *(const bf16x8*)(Bh + off);
            b_l[c] = *(const bf16x8*)(Bl + off);
        }
#pragma unroll
        for (int r = 0; r < 2; ++r)
#pragma unroll
            for (int c = 0; c < 4; ++c) {
                acc[r][c] = __builtin_amdgcn_mfma_f32_16x16x32_bf16(a_h[r], b_h[c], acc[r][c], 0, 0, 0);
                acc[r][c] = __builtin_amdgcn_mfma_f32_16x16x32_bf16(a_h[r], b_l[c], acc[r][c], 0, 0, 0);
                acc[r][c] = __builtin_amdgcn_mfma_f32_16x16x32_bf16(a_l[r], b_h[c], acc[r][c], 0, 0, 0);
            }
    }

    // C/D layout: col = lane&15, row = quad*4 + reg  [measured m89/m91]
#pragma unroll
    for (int r = 0; r < 2; ++r)
#pragma unroll
        for (int c = 0; c < 4; ++c) {
            int col = col0 + c * 16 + l16;
#pragma unroll
            for (int reg = 0; reg < 4; ++reg) {
                int row = row0 + r * 16 + quad * 4 + reg;
                __builtin_nontemporal_store(acc[r][c][reg], &out[(size_t)row * 256 + col]);
            }
        }

    // fused layer-1 scores: head == wave
    float at[4], an[4];
#pragma unroll
    for (int c = 0; c < 4; ++c) {
        at[c] = avec[wave * 128 + c * 16 + l16];
        an[c] = avec[wave * 128 + 64 + c * 16 + l16];
    }
#pragma unroll
    for (int r = 0; r < 2; ++r) {
        float pt[4] = {0.f, 0.f, 0.f, 0.f}, pn[4] = {0.f, 0.f, 0.f, 0.f};
#pragma unroll
        for (int c = 0; c < 4; ++c)
#pragma unroll
            for (int reg = 0; reg < 4; ++reg) {
                pt[reg] += acc[r][c][reg] * at[c];
                pn[reg] += acc[r][c][reg] * an[c];
            }
#pragma unroll
        for (int reg = 0; reg < 4; ++reg)
#pragma unroll
            for (int m = 1; m < 16; m <<= 1) {
                pt[reg] += __shfl_xor(pt[reg], m);
                pn[reg] += __shfl_xor(pn[reg], m);
            }
        if (l16 == 0) {
#pragma unroll
            for (int reg = 0; reg < 4; ++reg) {
                int row = row0 + r * 16 + quad * 4 + reg;
                __builtin_nontemporal_store(pt[reg], &s_t[wave * N2C + row]);
                __builtin_nontemporal_store(pn[reg], &s_n[wave * N2C + row]);
            }
        }
    }
}

// ---------------- K2: att1 — one target/block (4000 blocks, high TLP for gather) ----
__global__ __launch_bounds__(256) void att_kernel(
    const float* __restrict__ hprev, const int* __restrict__ nbr_arr,
    const float* __restrict__ s_t, const float* __restrict__ s_n,
    ushort* __restrict__ outhi, ushort* __restrict__ outlo, int T, int Nsrc)
{
    __shared__ int nbr[DEG + 1];
    __shared__ float att_s[NHEAD][DEG + 3];
    __shared__ float4 red[4][64];
    const int tgt = blockIdx.x;
    const int t = threadIdx.x;
    const int lane = t & 63;
    if (t < DEG) nbr[t] = nbr_arr[tgt * DEG + t];
    else if (t == DEG) nbr[DEG] = nbr_arr[T * DEG + tgt];  // self-loop edge
    __syncthreads();

    {   // wave = head; lane = edge index (33 edges), lanes 33..63 inert
        const int hd = t >> 6;
        int me = (lane <= DEG) ? nbr[lane] : -1;
        int k = (lane <= DEG) ? 1 : 0;
#pragma unroll
        for (int j = 0; j < DEG; ++j) {          // dedupe scan via shuffle
            int v = __shfl(me, j);
            if (j < lane && v == me) k = 0;
        }
        float e = s_t[hd * Nsrc + tgt] + ((lane <= DEG) ? s_n[hd * Nsrc + me] : 0.f);
        e = (e >= 0.f) ? e : ALPHA * e;          // LeakyReLU(0.2)
        float em = k ? e : -1e30f;
        float m = em;
#pragma unroll
        for (int off = 1; off < 64; off <<= 1) m = fmaxf(m, __shfl_xor(m, off));
        float w = k ? __expf(e - m) : 0.f;
        float Z = w;
#pragma unroll
        for (int off = 1; off < 64; off <<= 1) Z += __shfl_xor(Z, off);
        if (lane <= DEG) att_s[hd][lane] = w / Z;
    }
    __syncthreads();

    // aggregation: thread = (rg = t>>6 row-group, cq = t&63 channel-quad)
    const int cq = t & 63;
    const int rg = t >> 6;
    const int hd = cq >> 4;
    const float4* hp4 = (const float4*)hprev;
    float4 acc = make_float4(0.f, 0.f, 0.f, 0.f);
#pragma unroll
    for (int ii = 0; ii < 9; ++ii) {
        int i = rg + ii * 4;
        if (i <= DEG) {
            float w = att_s[hd][i];                       // dup edges: w==0
            float4 v = hp4[(size_t)nbr[i] * 64 + cq];
            acc.x += w * v.x; acc.y += w * v.y;
            acc.z += w * v.z; acc.w += w * v.w;
        }
    }
    red[rg][cq] = acc;
    __syncthreads();
    if (t < 64) {
        float4 s0 = red[0][t], s1 = red[1][t], s2 = red[2][t], s3 = red[3][t];
        float4 s;
        s.x = s0.x + s1.x + s2.x + s3.x;
        s.y = s0.y + s1.y + s2.y + s3.y;
        s.z = s0.z + s1.z + s2.z + s3.z;
        s.w = s0.w + s1.w + s2.w + s3.w;
        s.x = (s.x > 0.f) ? s.x : expm1f(s.x);   // ELU
        s.y = (s.y > 0.f) ? s.y : expm1f(s.y);
        s.z = (s.z > 0.f) ? s.z : expm1f(s.z);
        s.w = (s.w > 0.f) ? s.w : expm1f(s.w);
        ushort hx = f2bf(s.x), hy = f2bf(s.y), hz = f2bf(s.z), hw = f2bf(s.w);
        ushort lx = f2bf(s.x - bf2f(hx)), ly = f2bf(s.y - bf2f(hy));
        ushort lz = f2bf(s.z - bf2f(hz)), lw = f2bf(s.w - bf2f(hw));
        __builtin_nontemporal_store(pack4(hx, hy, hz, hw),
            &((unsigned long long*)outhi)[tgt * 64 + t]);
        __builtin_nontemporal_store(pack4(lx, ly, lz, lw),
            &((unsigned long long*)outlo)[tgt * 64 + t]);
    }
}

// ---------------- K3: gemm2 = x1 @ Wc1 (A bf16 hi/lo from global) + layer-2 scores --
// 250 blocks x 16 rows.
__global__ __launch_bounds__(256) void gemm2_kernel(
    const ushort* __restrict__ Ah, const ushort* __restrict__ Al,
    const ushort* __restrict__ Bh, const ushort* __restrict__ Bl,
    const float* __restrict__ avec,
    float* __restrict__ h1, float* __restrict__ st2, float* __restrict__ sn2)
{
    const int wave = threadIdx.x >> 6, lane = threadIdx.x & 63;
    const int quad = lane >> 4, l16 = lane & 15;
    const int row0 = blockIdx.x * 16;            // 250*16 = 4000 exactly
    const int col0 = wave * 64;
    const int kbase = quad * 8;
    const int arow = row0 + l16;

    f32x4 acc2[4];
#pragma unroll
    for (int c = 0; c < 4; ++c) acc2[c] = (f32x4){0.f, 0.f, 0.f, 0.f};

    for (int k0 = 0; k0 < 256; k0 += 32) {
        bf16x8 a_h, a_l, b_h[4], b_l[4];
        int aoff = arow * 256 + k0 + kbase;
        a_h = *(const bf16x8*)(Ah + aoff);
        a_l = *(const bf16x8*)(Al + aoff);
#pragma unroll
        for (int c = 0; c < 4; ++c) {
            int off = (col0 + c * 16 + l16) * 256 + k0 + kbase;
            b_h[c] = *(const bf16x8*)(Bh + off);
            b_l[c] = *(const bf16x8*)(Bl + off);
        }
#pragma unroll
        for (int c = 0; c < 4; ++c) {
            acc2[c] = __builtin_amdgcn_mfma_f32_16x16x32_bf16(a_h, b_h[c], acc2[c], 0, 0, 0);
            acc2[c] = __builtin_amdgcn_mfma_f32_16x16x32_bf16(a_h, b_l[c], acc2[c], 0, 0, 0);
            acc2[c] = __builtin_amdgcn_mfma_f32_16x16x32_bf16(a_l, b_h[c], acc2[c], 0, 0, 0);
        }
    }
#pragma unroll
    for (int c = 0; c < 4; ++c) {
        int col = col0 + c * 16 + l16;
#pragma unroll
        for (int reg = 0; reg < 4; ++reg) {
            int row = row0 + quad * 4 + reg;
            __builtin_nontemporal_store(acc2[c][reg], &h1[(size_t)row * 256 + col]);
        }
    }

    // fused layer-2 scores (head == wave)
    float at[4], an[4];
#pragma unroll
    for (int c = 0; c < 4; ++c) {
        at[c] = avec[wave * 128 + c * 16 + l16];
        an[c] = avec[wave * 128 + 64 + c * 16 + l16];
    }
    float pt[4] = {0.f, 0.f, 0.f, 0.f}, pn[4] = {0.f, 0.f, 0.f, 0.f};
#pragma unroll
    for (int c = 0; c < 4; ++c)
#pragma unroll
        for (int reg = 0; reg < 4; ++reg) {
            pt[reg] += acc2[c][reg] * at[c];
            pn[reg] += acc2[c][reg] * an[c];
        }
#pragma unroll
    for (int reg = 0; reg < 4; ++reg)
#pragma unroll
        for (int m = 1; m < 16; m <<= 1) {
            pt[reg] += __shfl_xor(pt[reg], m);
            pn[reg] += __shfl_xor(pn[reg], m);
        }
    if (l16 == 0) {
#pragma unroll
        for (int reg = 0; reg < 4; ++reg) {
            int row = row0 + quad * 4 + reg;
            __builtin_nontemporal_store(pt[reg], &st2[wave * N1C + row]);
            __builtin_nontemporal_store(pn[reg], &sn2[wave * N1C + row]);
        }
    }
}

// ---------------- K4: att2 + final Linear + Tanh (4 targets/block, wave = target) ---
// Round-9 change: final matvec reads TRANSPOSED linWT coalesced (at fixed k, 64 lanes
// read 256 contiguous bytes) instead of linW rows at 1KB lane-stride (64 lines/wave).
__global__ __launch_bounds__(256) void att_lin_kernel(
    const float* __restrict__ h1, const int* __restrict__ nbr_arr,
    const float* __restrict__ s_t, const float* __restrict__ s_n,
    const float* __restrict__ linWT, const float* __restrict__ bias,
    float* __restrict__ out)
{
    __shared__ int   nbr_s[4][DEG + 1];
    __shared__ float att_w[4][NHEAD][DEG + 1];
    __shared__ float x2[4][256];

    const int wave = threadIdx.x >> 6, lane = threadIdx.x & 63;
    const int blk = blockIdx.x;                  // 250 blocks * 4 targets = 1000

    for (int idx = threadIdx.x; idx < 4 * (DEG + 1); idx += 256) {
        int tt = idx / (DEG + 1), e = idx - tt * (DEG + 1);
        nbr_s[tt][e] = (e < DEG) ? nbr_arr[(blk * 4 + tt) * DEG + e]
                                 : nbr_arr[N0C * DEG + blk * 4 + tt];
    }
    __syncthreads();

    {
        const int tl = wave;
        const int gt = blk * 4 + tl;
        int me = (lane <= DEG) ? nbr_s[tl][lane] : 0;
        int k = (lane <= DEG) ? 1 : 0;
#pragma unroll
        for (int j = 0; j < DEG; ++j) {
            int v = __shfl(me, j);
            if (j < lane && v == me) k = 0;
        }
#pragma unroll
        for (int hd = 0; hd < NHEAD; ++hd) {
            float e = s_t[hd * N1C + gt] + s_n[hd * N1C + me];
            e = (e >= 0.f) ? e : ALPHA * e;
            float em = k ? e : -1e30f;
            float m = em;
#pragma unroll
            for (int off = 1; off < 64; off <<= 1) m = fmaxf(m, __shfl_xor(m, off));
            float w = k ? __expf(e - m) : 0.f;
            float Z = w;
#pragma unroll
            for (int off = 1; off < 64; off <<= 1) Z += __shfl_xor(Z, off);
            if (lane <= DEG) att_w[tl][hd][lane] = w / Z;
        }
    }
    __syncthreads();
    {
        const int tl = wave;
        const int hh = lane >> 4;
        float4 acc = make_float4(0.f, 0.f, 0.f, 0.f);
#pragma unroll
        for (int e = 0; e <= DEG; ++e) {
            float w = att_w[tl][hh][e];
            float4 v = ((const float4*)h1)[(size_t)nbr_s[tl][e] * 64 + lane];
            acc.x += w * v.x; acc.y += w * v.y;
            acc.z += w * v.z; acc.w += w * v.w;
        }
        acc.x = (acc.x > 0.f) ? acc.x : expm1f(acc.x);   // ELU
        acc.y = (acc.y > 0.f) ? acc.y : expm1f(acc.y);
        acc.z = (acc.z > 0.f) ? acc.z : expm1f(acc.z);
        acc.w = (acc.w > 0.f) ? acc.w : expm1f(acc.w);
        *(float4*)(&x2[tl][lane * 4]) = acc;
    }
    __syncthreads();

    // final linear: thread = output channel c; coalesced stream over linWT rows.
    // x2[tl][k] is a same-address LDS broadcast across the wave (free).
    const int c = threadIdx.x;
    float v0 = 0.f, v1 = 0.f, v2 = 0.f, v3 = 0.f;
#pragma unroll 8
    for (int k = 0; k < 256; ++k) {
        float wv = linWT[k * 256 + c];
        v0 += x2[0][k] * wv;
        v1 += x2[1][k] * wv;
        v2 += x2[2][k] * wv;
        v3 += x2[3][k] * wv;
    }
    float b = bias[c];
    out[(size_t)(blk * 4 + 0) * 256 + c] = tanhf(v0 + b);
    out[(size_t)(blk * 4 + 1) * 256 + c] = tanhf(v1 + b);
    out[(size_t)(blk * 4 + 2) * 256 + c] = tanhf(v2 + b);
    out[(size_t)(blk * 4 + 3) * 256 + c] = tanhf(v3 + b);
}

extern "C" void kernel_launch(void* const* d_in, const int* in_sizes, int n_in,
                              void* d_out, int out_size, void* d_ws, size_t ws_size,
                              hipStream_t stream)
{
    const float* x    = (const float*)d_in[0];
    const float* W0   = (const float*)d_in[1];
    const float* a0   = (const float*)d_in[2];
    const float* W1   = (const float*)d_in[3];
    const float* a1   = (const float*)d_in[4];
    const float* linW = (const float*)d_in[5];
    const float* linb = (const float*)d_in[6];
    const int* adj1_nbr = (const int*)d_in[8];
    const int* adj0_nbr = (const int*)d_in[10];

    char* base = (char*)d_ws;
    ushort* Wth = (ushort*)base;                 // 2*65536 ushort = 256 KB
    ushort* Wtl = (ushort*)(base + 262144);      // 256 KB          (ends 524288)
    float*  linWT = (float*)(base + 524288);     // 256x256 f32 = 256 KB (ends 786432)
    float*  st  = (float*)(base + 786432);       // 4*16000 f32 (256 KB slot)
    float*  sn  = (float*)(base + 1048576);      //                 (ends 1310720)
    float*  st2 = (float*)(base + 1310720);      // 4*4000 f32 (64 KB slot)
    float*  sn2 = (float*)(base + 1376256);      //                 (ends 1441792)
    ushort* xhi = (ushort*)(base + 1441792);     // 4000*256 u16 = 2 MB
    ushort* xlo = (ushort*)(base + 3538944);     // 2 MB            (ends 5636096)
    float*  h0  = (float*)(base + 5636096);      // 16000*256 f32 = 16 MB
    float*  h1  = (float*)(base + 22020096);     // 4000*256 f32 = 4 MB (ends ~26 MB)

    // K0: weight repack (W0,W1 -> bf16 hi/lo, [n][k]) + linW transpose (fp32)
    repack_kernel<<<768, 256, 0, stream>>>(W0, W1, linW, Wth, Wtl, linWT);

    // K1: h0 = x @ Wc0 + layer-1 scores
    gemm1_kernel<<<N2C / 32, 256, 0, stream>>>(x, Wth, Wtl, a0, h0, st, sn);

    // K2: att1 (4000 blocks — TLP hides gather latency)
    att_kernel<<<N1C, 256, 0, stream>>>(h0, adj1_nbr, st, sn, xhi, xlo, N1C, N2C);

    // K3: gemm2 = x1 @ Wc1 + layer-2 scores
    gemm2_kernel<<<N1C / 16, 256, 0, stream>>>(
        xhi, xlo, Wth + 65536, Wtl + 65536, a1, h1, st2, sn2);

    // K4: att2 -> Linear+Tanh (coalesced linWT)
    att_lin_kernel<<<N0C / 4, 256, 0, stream>>>(
        h1, adj0_nbr, st2, sn2, linWT, linb, (float*)d_out);
}

// Round 10
// 161.604 us; speedup vs baseline: 1.0636x; 1.0312x over previous
//
#include <hip/hip_runtime.h>
#include <math.h>

#define N2C 16000
#define N1C 4000
#define N0C 1000
#define DEG 32
#define NHEAD 4
#define ALPHA 0.2f
#define LDP 264     // padded LDS row pitch (ushorts): 264*2=528 B, 16B-aligned, 2-way banks

typedef __attribute__((ext_vector_type(8))) short bf16x8;
typedef __attribute__((ext_vector_type(4))) float f32x4;

__device__ __forceinline__ ushort f2bf(float f) {
    unsigned u = __float_as_uint(f);
    unsigned r = (u + 0x7fffu + ((u >> 16) & 1u)) >> 16;   // RTNE
    return (ushort)r;
}
__device__ __forceinline__ float bf2f(ushort h) {
    return __uint_as_float(((unsigned)h) << 16);
}
__device__ __forceinline__ unsigned long long pack4(ushort a, ushort b, ushort c, ushort d) {
    return (unsigned long long)a | ((unsigned long long)b << 16) |
           ((unsigned long long)c << 32) | ((unsigned long long)d << 48);
}

// ---------------- K0: repack W0 only -> bf16 hi/lo [n][k] (256 blocks) --------------
// W1 repack + linW transpose moved into att1's tail blocks (their consumers are K3/K4).
__global__ __launch_bounds__(256) void repack_kernel(
    const float* __restrict__ W0,
    ushort* __restrict__ Wth, ushort* __restrict__ Wtl)
{
    int g = blockIdx.x * 256 + threadIdx.x;   // 0 .. 65535
    int c = g >> 8, k = g & 255;
    float v = W0[(c >> 6) * (256 * 64) + k * 64 + (c & 63)];
    ushort h = f2bf(v);
    __builtin_nontemporal_store(h, &Wth[g]);
    __builtin_nontemporal_store(f2bf(v - bf2f(h)), &Wtl[g]);
}

// ---------------- K1: h0(bf16) = x @ Wc0 (split-bf16 MFMA) + layer-1 scores --------
// Round-10: h0 stored as SINGLE bf16 (8 MB not 16 MB) — only consumer is att1's
// weighted aggregate; halves the 132 MB gather. Scores still computed from fp32 acc.
__global__ __launch_bounds__(256) void gemm1_kernel(
    const float* __restrict__ Af,
    const ushort* __restrict__ Bh, const ushort* __restrict__ Bl,
    const float* __restrict__ avec,
    ushort* __restrict__ outb, float* __restrict__ s_t, float* __restrict__ s_n)
{
    __shared__ ushort sah[32 * LDP];
    __shared__ ushort sal[32 * LDP];
    const int wave = threadIdx.x >> 6, lane = threadIdx.x & 63;
    const int quad = lane >> 4, l16 = lane & 15;
    const int row0 = blockIdx.x * 32;            // 500*32 = 16000 exactly, no clamp
    const int col0 = wave * 64;

    for (int idx = threadIdx.x; idx < 32 * 64; idx += 256) {
        int row = idx >> 6, c4 = idx & 63;
        float4 f = ((const float4*)Af)[(size_t)(row0 + row) * 64 + c4];
        ushort4 h, l;
        h.x = f2bf(f.x); l.x = f2bf(f.x - bf2f(h.x));
        h.y = f2bf(f.y); l.y = f2bf(f.y - bf2f(h.y));
        h.z = f2bf(f.z); l.z = f2bf(f.z - bf2f(h.z));
        h.w = f2bf(f.w); l.w = f2bf(f.w - bf2f(h.w));
        *(ushort4*)(&sah[row * LDP + c4 * 4]) = h;
        *(ushort4*)(&sal[row * LDP + c4 * 4]) = l;
    }
    __syncthreads();

    f32x4 acc[2][4];
#pragma unroll
    for (int r = 0; r < 2; ++r)
#pragma unroll
        for (int c = 0; c < 4; ++c) acc[r][c] = (f32x4){0.f, 0.f, 0.f, 0.f};
    const int kbase = quad * 8;

    for (int k0 = 0; k0 < 256; k0 += 32) {
        bf16x8 a_h[2], a_l[2], b_h[4], b_l[4];
#pragma unroll
        for (int r = 0; r < 2; ++r) {
            int loff = (r * 16 + l16) * LDP + k0 + kbase;
            a_h[r] = *(const bf16x8*)(&sah[loff]);
            a_l[r] = *(const bf16x8*)(&sal[loff]);
        }
#pragma unroll
        for (int c = 0; c < 4; ++c) {
            int off = (col0 + c * 16 + l16) * 256 + k0 + kbase;
            b_h[c] = *(const bf16x8*)(Bh + off);
            b_l[c] = *(const bf16x8*)(Bl + off);
        }
#pragma unroll
        for (int r = 0; r < 2; ++r)
#pragma unroll
            for (int c = 0; c < 4; ++c) {
                acc[r][c] = __builtin_amdgcn_mfma_f32_16x16x32_bf16(a_h[r], b_h[c], acc[r][c], 0, 0, 0);
                acc[r][c] = __builtin_amdgcn_mfma_f32_16x16x32_bf16(a_h[r], b_l[c], acc[r][c], 0, 0, 0);
                acc[r][c] = __builtin_amdgcn_mfma_f32_16x16x32_bf16(a_l[r], b_h[c], acc[r][c], 0, 0, 0);
            }
    }

    // C/D layout: col = lane&15, row = quad*4 + reg  [measured m89/m91]
#pragma unroll
    for (int r = 0; r < 2; ++r)
#pragma unroll
        for (int c = 0; c < 4; ++c) {
            int col = col0 + c * 16 + l16;
#pragma unroll
            for (int reg = 0; reg < 4; ++reg) {
                int row = row0 + r * 16 + quad * 4 + reg;
                __builtin_nontemporal_store(f2bf(acc[r][c][reg]),
                                            &outb[(size_t)row * 256 + col]);
            }
        }

    // fused layer-1 scores: head == wave (from fp32 acc — exact as before)
    float at[4], an[4];
#pragma unroll
    for (int c = 0; c < 4; ++c) {
        at[c] = avec[wave * 128 + c * 16 + l16];
        an[c] = avec[wave * 128 + 64 + c * 16 + l16];
    }
#pragma unroll
    for (int r = 0; r < 2; ++r) {
        float pt[4] = {0.f, 0.f, 0.f, 0.f}, pn[4] = {0.f, 0.f, 0.f, 0.f};
#pragma unroll
        for (int c = 0; c < 4; ++c)
#pragma unroll
            for (int reg = 0; reg < 4; ++reg) {
                pt[reg] += acc[r][c][reg] * at[c];
                pn[reg] += acc[r][c][reg] * an[c];
            }
#pragma unroll
        for (int reg = 0; reg < 4; ++reg)
#pragma unroll
            for (int m = 1; m < 16; m <<= 1) {
                pt[reg] += __shfl_xor(pt[reg], m);
                pn[reg] += __shfl_xor(pn[reg], m);
            }
        if (l16 == 0) {
#pragma unroll
            for (int reg = 0; reg < 4; ++reg) {
                int row = row0 + r * 16 + quad * 4 + reg;
                __builtin_nontemporal_store(pt[reg], &s_t[wave * N2C + row]);
                __builtin_nontemporal_store(pn[reg], &s_n[wave * N2C + row]);
            }
        }
    }
}

// ---------------- K2: att1 (4000 blocks) + piggybacked W1-repack/linWT tail ---------
// Blocks [0,4000): attention. [4000,4256): W1 -> bf16 hi/lo. [4256,4512): linW^T.
// Tail work's consumers are K3/K4, so ordering is satisfied by kernel boundaries.
__global__ __launch_bounds__(256) void att_kernel(
    const ushort* __restrict__ h0b, const int* __restrict__ nbr_arr,
    const float* __restrict__ s_t, const float* __restrict__ s_n,
    const float* __restrict__ W1, const float* __restrict__ linW,
    ushort* __restrict__ Wth, ushort* __restrict__ Wtl, float* __restrict__ linWT,
    ushort* __restrict__ outhi, ushort* __restrict__ outlo)
{
    const int b = blockIdx.x;
    if (b >= N1C) {
        if (b < N1C + 256) {   // W1 repack -> Wth/Wtl at offset 65536
            int idx = (b - N1C) * 256 + threadIdx.x;   // 0..65535
            int c = idx >> 8, k = idx & 255;
            float v = W1[(c >> 6) * (256 * 64) + k * 64 + (c & 63)];
            ushort h = f2bf(v);
            __builtin_nontemporal_store(h, &Wth[65536 + idx]);
            __builtin_nontemporal_store(f2bf(v - bf2f(h)), &Wtl[65536 + idx]);
        } else {               // linW transpose (fp32)
            int idx = (b - N1C - 256) * 256 + threadIdx.x;
            int k = idx >> 8, c = idx & 255;
            __builtin_nontemporal_store(linW[c * 256 + k], &linWT[k * 256 + c]);
        }
        return;
    }

    __shared__ int nbr[DEG + 1];
    __shared__ float att_s[NHEAD][DEG + 3];
    __shared__ float4 red[4][64];
    const int tgt = b;
    const int t = threadIdx.x;
    const int lane = t & 63;
    if (t < DEG) nbr[t] = nbr_arr[tgt * DEG + t];
    else if (t == DEG) nbr[DEG] = nbr_arr[N1C * DEG + tgt];  // self-loop edge
    __syncthreads();

    {   // wave = head; lane = edge index (33 edges), lanes 33..63 inert
        const int hd = t >> 6;
        int me = (lane <= DEG) ? nbr[lane] : -1;
        int k = (lane <= DEG) ? 1 : 0;
#pragma unroll
        for (int j = 0; j < DEG; ++j) {          // dedupe scan via shuffle
            int v = __shfl(me, j);
            if (j < lane && v == me) k = 0;
        }
        float e = s_t[hd * N2C + tgt] + ((lane <= DEG) ? s_n[hd * N2C + me] : 0.f);
        e = (e >= 0.f) ? e : ALPHA * e;          // LeakyReLU(0.2)
        float em = k ? e : -1e30f;
        float m = em;
#pragma unroll
        for (int off = 1; off < 64; off <<= 1) m = fmaxf(m, __shfl_xor(m, off));
        float w = k ? __expf(e - m) : 0.f;
        float Z = w;
#pragma unroll
        for (int off = 1; off < 64; off <<= 1) Z += __shfl_xor(Z, off);
        if (lane <= DEG) att_s[hd][lane] = w / Z;
    }
    __syncthreads();

    // aggregation: thread = (rg = t>>6 row-group, cq = t&63 channel-quad)
    // h0 is bf16: u64 load = 4 channels (halved gather bytes vs fp32)
    const int cq = t & 63;
    const int rg = t >> 6;
    const int hd = cq >> 4;
    const unsigned long long* hp8 = (const unsigned long long*)h0b;
    float4 acc = make_float4(0.f, 0.f, 0.f, 0.f);
#pragma unroll
    for (int ii = 0; ii < 9; ++ii) {
        int i = rg + ii * 4;
        if (i <= DEG) {
            float w = att_s[hd][i];                       // dup edges: w==0
            unsigned long long p = hp8[(size_t)nbr[i] * 64 + cq];
            acc.x += w * bf2f((ushort)p);
            acc.y += w * bf2f((ushort)(p >> 16));
            acc.z += w * bf2f((ushort)(p >> 32));
            acc.w += w * bf2f((ushort)(p >> 48));
        }
    }
    red[rg][cq] = acc;
    __syncthreads();
    if (t < 64) {
        float4 s0 = red[0][t], s1 = red[1][t], s2 = red[2][t], s3 = red[3][t];
        float4 s;
        s.x = s0.x + s1.x + s2.x + s3.x;
        s.y = s0.y + s1.y + s2.y + s3.y;
        s.z = s0.z + s1.z + s2.z + s3.z;
        s.w = s0.w + s1.w + s2.w + s3.w;
        s.x = (s.x > 0.f) ? s.x : expm1f(s.x);   // ELU
        s.y = (s.y > 0.f) ? s.y : expm1f(s.y);
        s.z = (s.z > 0.f) ? s.z : expm1f(s.z);
        s.w = (s.w > 0.f) ? s.w : expm1f(s.w);
        ushort hx = f2bf(s.x), hy = f2bf(s.y), hz = f2bf(s.z), hw = f2bf(s.w);
        ushort lx = f2bf(s.x - bf2f(hx)), ly = f2bf(s.y - bf2f(hy));
        ushort lz = f2bf(s.z - bf2f(hz)), lw = f2bf(s.w - bf2f(hw));
        __builtin_nontemporal_store(pack4(hx, hy, hz, hw),
            &((unsigned long long*)outhi)[tgt * 64 + t]);
        __builtin_nontemporal_store(pack4(lx, ly, lz, lw),
            &((unsigned long long*)outlo)[tgt * 64 + t]);
    }
}

// ---------------- K3: gemm2 = x1 @ Wc1 (A bf16 hi/lo from global) + layer-2 scores --
// 250 blocks x 16 rows.
__global__ __launch_bounds__(256) void gemm2_kernel(
    const ushort* __restrict__ Ah, const ushort* __restrict__ Al,
    const ushort* __restrict__ Bh, const ushort* __restrict__ Bl,
    const float* __restrict__ avec,
    float* __restrict__ h1, float* __restrict__ st2, float* __restrict__ sn2)
{
    const int wave = threadIdx.x >> 6, lane = threadIdx.x & 63;
    const int quad = lane >> 4, l16 = lane & 15;
    const int row0 = blockIdx.x * 16;            // 250*16 = 4000 exactly
    const int col0 = wave * 64;
    const int kbase = quad * 8;
    const int arow = row0 + l16;

    f32x4 acc2[4];
#pragma unroll
    for (int c = 0; c < 4; ++c) acc2[c] = (f32x4){0.f, 0.f, 0.f, 0.f};

    for (int k0 = 0; k0 < 256; k0 += 32) {
        bf16x8 a_h, a_l, b_h[4], b_l[4];
        int aoff = arow * 256 + k0 + kbase;
        a_h = *(const bf16x8*)(Ah + aoff);
        a_l = *(const bf16x8*)(Al + aoff);
#pragma unroll
        for (int c = 0; c < 4; ++c) {
            int off = (col0 + c * 16 + l16) * 256 + k0 + kbase;
            b_h[c] = *(const bf16x8*)(Bh + off);
            b_l[c] = *(const bf16x8*)(Bl + off);
        }
#pragma unroll
        for (int c = 0; c < 4; ++c) {
            acc2[c] = __builtin_amdgcn_mfma_f32_16x16x32_bf16(a_h, b_h[c], acc2[c], 0, 0, 0);
            acc2[c] = __builtin_amdgcn_mfma_f32_16x16x32_bf16(a_h, b_l[c], acc2[c], 0, 0, 0);
            acc2[c] = __builtin_amdgcn_mfma_f32_16x16x32_bf16(a_l, b_h[c], acc2[c], 0, 0, 0);
        }
    }
#pragma unroll
    for (int c = 0; c < 4; ++c) {
        int col = col0 + c * 16 + l16;
#pragma unroll
        for (int reg = 0; reg < 4; ++reg) {
            int row = row0 + quad * 4 + reg;
            __builtin_nontemporal_store(acc2[c][reg], &h1[(size_t)row * 256 + col]);
        }
    }

    // fused layer-2 scores (head == wave)
    float at[4], an[4];
#pragma unroll
    for (int c = 0; c < 4; ++c) {
        at[c] = avec[wave * 128 + c * 16 + l16];
        an[c] = avec[wave * 128 + 64 + c * 16 + l16];
    }
    float pt[4] = {0.f, 0.f, 0.f, 0.f}, pn[4] = {0.f, 0.f, 0.f, 0.f};
#pragma unroll
    for (int c = 0; c < 4; ++c)
#pragma unroll
        for (int reg = 0; reg < 4; ++reg) {
            pt[reg] += acc2[c][reg] * at[c];
            pn[reg] += acc2[c][reg] * an[c];
        }
#pragma unroll
    for (int reg = 0; reg < 4; ++reg)
#pragma unroll
        for (int m = 1; m < 16; m <<= 1) {
            pt[reg] += __shfl_xor(pt[reg], m);
            pn[reg] += __shfl_xor(pn[reg], m);
        }
    if (l16 == 0) {
#pragma unroll
        for (int reg = 0; reg < 4; ++reg) {
            int row = row0 + quad * 4 + reg;
            __builtin_nontemporal_store(pt[reg], &st2[wave * N1C + row]);
            __builtin_nontemporal_store(pn[reg], &sn2[wave * N1C + row]);
        }
    }
}

// ---------------- K4: att2 + final Linear + Tanh (4 targets/block, wave = target) ---
__global__ __launch_bounds__(256) void att_lin_kernel(
    const float* __restrict__ h1, const int* __restrict__ nbr_arr,
    const float* __restrict__ s_t, const float* __restrict__ s_n,
    const float* __restrict__ linWT, const float* __restrict__ bias,
    float* __restrict__ out)
{
    __shared__ int   nbr_s[4][DEG + 1];
    __shared__ float att_w[4][NHEAD][DEG + 1];
    __shared__ float x2[4][256];

    const int wave = threadIdx.x >> 6, lane = threadIdx.x & 63;
    const int blk = blockIdx.x;                  // 250 blocks * 4 targets = 1000

    for (int idx = threadIdx.x; idx < 4 * (DEG + 1); idx += 256) {
        int tt = idx / (DEG + 1), e = idx - tt * (DEG + 1);
        nbr_s[tt][e] = (e < DEG) ? nbr_arr[(blk * 4 + tt) * DEG + e]
                                 : nbr_arr[N0C * DEG + blk * 4 + tt];
    }
    __syncthreads();

    {
        const int tl = wave;
        const int gt = blk * 4 + tl;
        int me = (lane <= DEG) ? nbr_s[tl][lane] : 0;
        int k = (lane <= DEG) ? 1 : 0;
#pragma unroll
        for (int j = 0; j < DEG; ++j) {
            int v = __shfl(me, j);
            if (j < lane && v == me) k = 0;
        }
#pragma unroll
        for (int hd = 0; hd < NHEAD; ++hd) {
            float e = s_t[hd * N1C + gt] + s_n[hd * N1C + me];
            e = (e >= 0.f) ? e : ALPHA * e;
            float em = k ? e : -1e30f;
            float m = em;
#pragma unroll
            for (int off = 1; off < 64; off <<= 1) m = fmaxf(m, __shfl_xor(m, off));
            float w = k ? __expf(e - m) : 0.f;
            float Z = w;
#pragma unroll
            for (int off = 1; off < 64; off <<= 1) Z += __shfl_xor(Z, off);
            if (lane <= DEG) att_w[tl][hd][lane] = w / Z;
        }
    }
    __syncthreads();
    {
        const int tl = wave;
        const int hh = lane >> 4;
        float4 acc = make_float4(0.f, 0.f, 0.f, 0.f);
#pragma unroll
        for (int e = 0; e <= DEG; ++e) {
            float w = att_w[tl][hh][e];
            float4 v = ((const float4*)h1)[(size_t)nbr_s[tl][e] * 64 + lane];
            acc.x += w * v.x; acc.y += w * v.y;
            acc.z += w * v.z; acc.w += w * v.w;
        }
        acc.x = (acc.x > 0.f) ? acc.x : expm1f(acc.x);   // ELU
        acc.y = (acc.y > 0.f) ? acc.y : expm1f(acc.y);
        acc.z = (acc.z > 0.f) ? acc.z : expm1f(acc.z);
        acc.w = (acc.w > 0.f) ? acc.w : expm1f(acc.w);
        *(float4*)(&x2[tl][lane * 4]) = acc;
    }
    __syncthreads();

    // final linear: thread = output channel c; coalesced stream over linWT rows.
    const int c = threadIdx.x;
    float v0 = 0.f, v1 = 0.f, v2 = 0.f, v3 = 0.f;
#pragma unroll 8
    for (int k = 0; k < 256; ++k) {
        float wv = linWT[k * 256 + c];
        v0 += x2[0][k] * wv;
        v1 += x2[1][k] * wv;
        v2 += x2[2][k] * wv;
        v3 += x2[3][k] * wv;
    }
    float b = bias[c];
    out[(size_t)(blk * 4 + 0) * 256 + c] = tanhf(v0 + b);
    out[(size_t)(blk * 4 + 1) * 256 + c] = tanhf(v1 + b);
    out[(size_t)(blk * 4 + 2) * 256 + c] = tanhf(v2 + b);
    out[(size_t)(blk * 4 + 3) * 256 + c] = tanhf(v3 + b);
}

extern "C" void kernel_launch(void* const* d_in, const int* in_sizes, int n_in,
                              void* d_out, int out_size, void* d_ws, size_t ws_size,
                              hipStream_t stream)
{
    const float* x    = (const float*)d_in[0];
    const float* W0   = (const float*)d_in[1];
    const float* a0   = (const float*)d_in[2];
    const float* W1   = (const float*)d_in[3];
    const float* a1   = (const float*)d_in[4];
    const float* linW = (const float*)d_in[5];
    const float* linb = (const float*)d_in[6];
    const int* adj1_nbr = (const int*)d_in[8];
    const int* adj0_nbr = (const int*)d_in[10];

    char* base = (char*)d_ws;
    ushort* Wth = (ushort*)base;                 // 2*65536 ushort = 256 KB
    ushort* Wtl = (ushort*)(base + 262144);      // 256 KB          (ends 524288)
    float*  linWT = (float*)(base + 524288);     // 256x256 f32 = 256 KB (ends 786432)
    float*  st  = (float*)(base + 786432);       // 4*16000 f32 (256 KB slot)
    float*  sn  = (float*)(base + 1048576);      //                 (ends 1310720)
    float*  st2 = (float*)(base + 1310720);      // 4*4000 f32 (64 KB slot)
    float*  sn2 = (float*)(base + 1376256);      //                 (ends 1441792)
    ushort* xhi = (ushort*)(base + 1441792);     // 4000*256 u16 = 2 MB
    ushort* xlo = (ushort*)(base + 3538944);     // 2 MB            (ends 5636096)
    ushort* h0b = (ushort*)(base + 5636096);     // 16000*256 bf16 = 8 MB
    float*  h1  = (float*)(base + 13824512);     // 4000*256 f32 = 4 MB (ends ~17.8 MB)

    // K0: W0 repack only (W1 + linWT piggyback inside att1)
    repack_kernel<<<256, 256, 0, stream>>>(W0, Wth, Wtl);

    // K1: h0(bf16) = x @ Wc0 + layer-1 scores
    gemm1_kernel<<<N2C / 32, 256, 0, stream>>>(x, Wth, Wtl, a0, h0b, st, sn);

    // K2: att1 (4000 blocks) + 512 tail blocks doing W1-repack / linW-transpose
    att_kernel<<<N1C + 512, 256, 0, stream>>>(
        h0b, adj1_nbr, st, sn, W1, linW, Wth, Wtl, linWT, xhi, xlo);

    // K3: gemm2 = x1 @ Wc1 + layer-2 scores
    gemm2_kernel<<<N1C / 16, 256, 0, stream>>>(
        xhi, xlo, Wth + 65536, Wtl + 65536, a1, h1, st2, sn2);

    // K4: att2 -> Linear+Tanh (coalesced linWT)
    att_lin_kernel<<<N0C / 4, 256, 0, stream>>>(
        h1, adj0_nbr, st2, sn2, linWT, linb, (float*)d_out);
}

// Round 12
// 159.514 us; speedup vs baseline: 1.0775x; 1.0131x over previous
//
#include <hip/hip_runtime.h>
#include <math.h>

#define N2C 16000
#define N1C 4000
#define N0C 1000
#define DEG 32
#define NHEAD 4
#define ALPHA 0.2f
#define LDP 264     // padded LDS row pitch (ushorts): 264*2=528 B, 16B-aligned, 2-way banks

typedef __attribute__((ext_vector_type(8))) short bf16x8;
typedef __attribute__((ext_vector_type(4))) float f32x4;

__device__ __forceinline__ ushort f2bf(float f) {
    unsigned u = __float_as_uint(f);
    unsigned r = (u + 0x7fffu + ((u >> 16) & 1u)) >> 16;   // RTNE
    return (ushort)r;
}
__device__ __forceinline__ float bf2f(ushort h) {
    return __uint_as_float(((unsigned)h) << 16);
}
__device__ __forceinline__ unsigned long long pack4(ushort a, ushort b, ushort c, ushort d) {
    return (unsigned long long)a | ((unsigned long long)b << 16) |
           ((unsigned long long)c << 32) | ((unsigned long long)d << 48);
}

// ---------------- K0: repack W0,W1 -> bf16 hi/lo, transposed to [n][k] --------------
__global__ __launch_bounds__(256) void repack_kernel(
    const float* __restrict__ W0, const float* __restrict__ W1,
    ushort* __restrict__ Wth, ushort* __restrict__ Wtl)
{
    int g = blockIdx.x * 256 + threadIdx.x;   // 0 .. 2*65536-1
    int mat = g >> 16;
    int idx = g & 65535;
    int c = idx >> 8, k = idx & 255;
    const float* W = mat ? W1 : W0;
    float v = W[(c >> 6) * (256 * 64) + k * 64 + (c & 63)];
    ushort h = f2bf(v);
    __builtin_nontemporal_store(h, &Wth[g]);                     // no dirty-L2 buildup
    __builtin_nontemporal_store(f2bf(v - bf2f(h)), &Wtl[g]);
}

// ---------------- K1: h0 = x @ Wc0 (split-bf16 MFMA) + layer-1 scores --------------
// A fp32 staged+converted once per block into LDS hi/lo; 500 blocks x 32 rows.
__global__ __launch_bounds__(256) void gemm1_kernel(
    const float* __restrict__ Af,
    const ushort* __restrict__ Bh, const ushort* __restrict__ Bl,
    const float* __restrict__ avec,
    float* __restrict__ out, float* __restrict__ s_t, float* __restrict__ s_n)
{
    __shared__ ushort sah[32 * LDP];
    __shared__ ushort sal[32 * LDP];
    const int wave = threadIdx.x >> 6, lane = threadIdx.x & 63;
    const int quad = lane >> 4, l16 = lane & 15;
    const int row0 = blockIdx.x * 32;            // 500*32 = 16000 exactly, no clamp
    const int col0 = wave * 64;

    for (int idx = threadIdx.x; idx < 32 * 64; idx += 256) {
        int row = idx >> 6, c4 = idx & 63;
        float4 f = ((const float4*)Af)[(size_t)(row0 + row) * 64 + c4];
        ushort4 h, l;
        h.x = f2bf(f.x); l.x = f2bf(f.x - bf2f(h.x));
        h.y = f2bf(f.y); l.y = f2bf(f.y - bf2f(h.y));
        h.z = f2bf(f.z); l.z = f2bf(f.z - bf2f(h.z));
        h.w = f2bf(f.w); l.w = f2bf(f.w - bf2f(h.w));
        *(ushort4*)(&sah[row * LDP + c4 * 4]) = h;
        *(ushort4*)(&sal[row * LDP + c4 * 4]) = l;
    }
    __syncthreads();

    f32x4 acc[2][4];
#pragma unroll
    for (int r = 0; r < 2; ++r)
#pragma unroll
        for (int c = 0; c < 4; ++c) acc[r][c] = (f32x4){0.f, 0.f, 0.f, 0.f};
    const int kbase = quad * 8;

    for (int k0 = 0; k0 < 256; k0 += 32) {
        bf16x8 a_h[2], a_l[2], b_h[4], b_l[4];
#pragma unroll
        for (int r = 0; r < 2; ++r) {
            int loff = (r * 16 + l16) * LDP + k0 + kbase;
            a_h[r] = *(const bf16x8*)(&sah[loff]);
            a_l[r] = *(const bf16x8*)(&sal[loff]);
        }
#pragma unroll
        for (int c = 0; c < 4; ++c) {
            int off = (col0 + c * 16 + l16) * 256 + k0 + kbase;
            b_h[c] = *(const bf16x8*)(Bh + off);
            b_l[c] = *(const bf16x8*)(Bl + off);
        }
#pragma unroll
        for (int r = 0; r < 2; ++r)
#pragma unroll
            for (int c = 0; c < 4; ++c) {
                acc[r][c] = __builtin_amdgcn_mfma_f32_16x16x32_bf16(a_h[r], b_h[c], acc[r][c], 0, 0, 0);
                acc[r][c] = __builtin_amdgcn_mfma_f32_16x16x32_bf16(a_h[r], b_l[c], acc[r][c], 0, 0, 0);
                acc[r][c] = __builtin_amdgcn_mfma_f32_16x16x32_bf16(a_l[r], b_h[c], acc[r][c], 0, 0, 0);
            }
    }

    // C/D layout: col = lane&15, row = quad*4 + reg  [measured m89/m91]
#pragma unroll
    for (int r = 0; r < 2; ++r)
#pragma unroll
        for (int c = 0; c < 4; ++c) {
            int col = col0 + c * 16 + l16;
#pragma unroll
            for (int reg = 0; reg < 4; ++reg) {
                int row = row0 + r * 16 + quad * 4 + reg;
                __builtin_nontemporal_store(acc[r][c][reg], &out[(size_t)row * 256 + col]);
            }
        }

    // fused layer-1 scores: head == wave
    float at[4], an[4];
#pragma unroll
    for (int c = 0; c < 4; ++c) {
        at[c] = avec[wave * 128 + c * 16 + l16];
        an[c] = avec[wave * 128 + 64 + c * 16 + l16];
    }
#pragma unroll
    for (int r = 0; r < 2; ++r) {
        float pt[4] = {0.f, 0.f, 0.f, 0.f}, pn[4] = {0.f, 0.f, 0.f, 0.f};
#pragma unroll
        for (int c = 0; c < 4; ++c)
#pragma unroll
            for (int reg = 0; reg < 4; ++reg) {
                pt[reg] += acc[r][c][reg] * at[c];
                pn[reg] += acc[r][c][reg] * an[c];
            }
#pragma unroll
        for (int reg = 0; reg < 4; ++reg)
#pragma unroll
            for (int m = 1; m < 16; m <<= 1) {
                pt[reg] += __shfl_xor(pt[reg], m);
                pn[reg] += __shfl_xor(pn[reg], m);
            }
        if (l16 == 0) {
#pragma unroll
            for (int reg = 0; reg < 4; ++reg) {
                int row = row0 + r * 16 + quad * 4 + reg;
                __builtin_nontemporal_store(pt[reg], &s_t[wave * N2C + row]);
                __builtin_nontemporal_store(pn[reg], &s_n[wave * N2C + row]);
            }
        }
    }
}

// ---------------- K2: att1 — one target/block (4000 blocks, high TLP for gather) ----
__global__ __launch_bounds__(256) void att_kernel(
    const float* __restrict__ hprev, const int* __restrict__ nbr_arr,
    const float* __restrict__ s_t, const float* __restrict__ s_n,
    ushort* __restrict__ outhi, ushort* __restrict__ outlo, int T, int Nsrc)
{
    __shared__ int nbr[DEG + 1];
    __shared__ float att_s[NHEAD][DEG + 3];
    __shared__ float4 red[4][64];
    const int tgt = blockIdx.x;
    const int t = threadIdx.x;
    const int lane = t & 63;
    if (t < DEG) nbr[t] = nbr_arr[tgt * DEG + t];
    else if (t == DEG) nbr[DEG] = nbr_arr[T * DEG + tgt];  // self-loop edge
    __syncthreads();

    {   // wave = head; lane = edge index (33 edges), lanes 33..63 inert
        const int hd = t >> 6;
        int me = (lane <= DEG) ? nbr[lane] : -1;
        int k = (lane <= DEG) ? 1 : 0;
#pragma unroll
        for (int j = 0; j < DEG; ++j) {          // dedupe scan via shuffle
            int v = __shfl(me, j);
            if (j < lane && v == me) k = 0;
        }
        float e = s_t[hd * Nsrc + tgt] + ((lane <= DEG) ? s_n[hd * Nsrc + me] : 0.f);
        e = (e >= 0.f) ? e : ALPHA * e;          // LeakyReLU(0.2)
        float em = k ? e : -1e30f;
        float m = em;
#pragma unroll
        for (int off = 1; off < 64; off <<= 1) m = fmaxf(m, __shfl_xor(m, off));
        float w = k ? __expf(e - m) : 0.f;
        float Z = w;
#pragma unroll
        for (int off = 1; off < 64; off <<= 1) Z += __shfl_xor(Z, off);
        if (lane <= DEG) att_s[hd][lane] = w / Z;
    }
    __syncthreads();

    // aggregation: thread = (rg = t>>6 row-group, cq = t&63 channel-quad)
    const int cq = t & 63;
    const int rg = t >> 6;
    const int hd = cq >> 4;
    const float4* hp4 = (const float4*)hprev;
    float4 acc = make_float4(0.f, 0.f, 0.f, 0.f);
#pragma unroll
    for (int ii = 0; ii < 9; ++ii) {
        int i = rg + ii * 4;
        if (i <= DEG) {
            float w = att_s[hd][i];                       // dup edges: w==0
            float4 v = hp4[(size_t)nbr[i] * 64 + cq];
            acc.x += w * v.x; acc.y += w * v.y;
            acc.z += w * v.z; acc.w += w * v.w;
        }
    }
    red[rg][cq] = acc;
    __syncthreads();
    if (t < 64) {
        float4 s0 = red[0][t], s1 = red[1][t], s2 = red[2][t], s3 = red[3][t];
        float4 s;
        s.x = s0.x + s1.x + s2.x + s3.x;
        s.y = s0.y + s1.y + s2.y + s3.y;
        s.z = s0.z + s1.z + s2.z + s3.z;
        s.w = s0.w + s1.w + s2.w + s3.w;
        s.x = (s.x > 0.f) ? s.x : expm1f(s.x);   // ELU
        s.y = (s.y > 0.f) ? s.y : expm1f(s.y);
        s.z = (s.z > 0.f) ? s.z : expm1f(s.z);
        s.w = (s.w > 0.f) ? s.w : expm1f(s.w);
        ushort hx = f2bf(s.x), hy = f2bf(s.y), hz = f2bf(s.z), hw = f2bf(s.w);
        ushort lx = f2bf(s.x - bf2f(hx)), ly = f2bf(s.y - bf2f(hy));
        ushort lz = f2bf(s.z - bf2f(hz)), lw = f2bf(s.w - bf2f(hw));
        __builtin_nontemporal_store(pack4(hx, hy, hz, hw),
            &((unsigned long long*)outhi)[tgt * 64 + t]);
        __builtin_nontemporal_store(pack4(lx, ly, lz, lw),
            &((unsigned long long*)outlo)[tgt * 64 + t]);
    }
}

// ---------------- K3: gemm2 = x1 @ Wc1 (A bf16 hi/lo from global) + layer-2 scores --
// 250 blocks x 16 rows.
__global__ __launch_bounds__(256) void gemm2_kernel(
    const ushort* __restrict__ Ah, const ushort* __restrict__ Al,
    const ushort* __restrict__ Bh, const ushort* __restrict__ Bl,
    const float* __restrict__ avec,
    float* __restrict__ h1, float* __restrict__ st2, float* __restrict__ sn2)
{
    const int wave = threadIdx.x >> 6, lane = threadIdx.x & 63;
    const int quad = lane >> 4, l16 = lane & 15;
    const int row0 = blockIdx.x * 16;            // 250*16 = 4000 exactly
    const int col0 = wave * 64;
    const int kbase = quad * 8;
    const int arow = row0 + l16;

    f32x4 acc2[4];
#pragma unroll
    for (int c = 0; c < 4; ++c) acc2[c] = (f32x4){0.f, 0.f, 0.f, 0.f};

    for (int k0 = 0; k0 < 256; k0 += 32) {
        bf16x8 a_h, a_l, b_h[4], b_l[4];
        int aoff = arow * 256 + k0 + kbase;
        a_h = *(const bf16x8*)(Ah + aoff);
        a_l = *(const bf16x8*)(Al + aoff);
#pragma unroll
        for (int c = 0; c < 4; ++c) {
            int off = (col0 + c * 16 + l16) * 256 + k0 + kbase;
            b_h[c] = *(const bf16x8*)(Bh + off);
            b_l[c] = *(const bf16x8*)(Bl + off);
        }
#pragma unroll
        for (int c = 0; c < 4; ++c) {
            acc2[c] = __builtin_amdgcn_mfma_f32_16x16x32_bf16(a_h, b_h[c], acc2[c], 0, 0, 0);
            acc2[c] = __builtin_amdgcn_mfma_f32_16x16x32_bf16(a_h, b_l[c], acc2[c], 0, 0, 0);
            acc2[c] = __builtin_amdgcn_mfma_f32_16x16x32_bf16(a_l, b_h[c], acc2[c], 0, 0, 0);
        }
    }
#pragma unroll
    for (int c = 0; c < 4; ++c) {
        int col = col0 + c * 16 + l16;
#pragma unroll
        for (int reg = 0; reg < 4; ++reg) {
            int row = row0 + quad * 4 + reg;
            __builtin_nontemporal_store(acc2[c][reg], &h1[(size_t)row * 256 + col]);
        }
    }

    // fused layer-2 scores (head == wave)
    float at[4], an[4];
#pragma unroll
    for (int c = 0; c < 4; ++c) {
        at[c] = avec[wave * 128 + c * 16 + l16];
        an[c] = avec[wave * 128 + 64 + c * 16 + l16];
    }
    float pt[4] = {0.f, 0.f, 0.f, 0.f}, pn[4] = {0.f, 0.f, 0.f, 0.f};
#pragma unroll
    for (int c = 0; c < 4; ++c)
#pragma unroll
        for (int reg = 0; reg < 4; ++reg) {
            pt[reg] += acc2[c][reg] * at[c];
            pn[reg] += acc2[c][reg] * an[c];
        }
#pragma unroll
    for (int reg = 0; reg < 4; ++reg)
#pragma unroll
        for (int m = 1; m < 16; m <<= 1) {
            pt[reg] += __shfl_xor(pt[reg], m);
            pn[reg] += __shfl_xor(pn[reg], m);
        }
    if (l16 == 0) {
#pragma unroll
        for (int reg = 0; reg < 4; ++reg) {
            int row = row0 + quad * 4 + reg;
            __builtin_nontemporal_store(pt[reg], &st2[wave * N1C + row]);
            __builtin_nontemporal_store(pn[reg], &sn2[wave * N1C + row]);
        }
    }
}

// ---------------- K4: att2 + final Linear + Tanh (4 targets/block, wave = target) ---
__global__ __launch_bounds__(256) void att_lin_kernel(
    const float* __restrict__ h1, const int* __restrict__ nbr_arr,
    const float* __restrict__ s_t, const float* __restrict__ s_n,
    const float* __restrict__ linW, const float* __restrict__ bias,
    float* __restrict__ out)
{
    __shared__ int   nbr_s[4][DEG + 1];
    __shared__ float att_w[4][NHEAD][DEG + 1];
    __shared__ float x2[4][256];

    const int wave = threadIdx.x >> 6, lane = threadIdx.x & 63;
    const int blk = blockIdx.x;                  // 250 blocks * 4 targets = 1000

    for (int idx = threadIdx.x; idx < 4 * (DEG + 1); idx += 256) {
        int tt = idx / (DEG + 1), e = idx - tt * (DEG + 1);
        nbr_s[tt][e] = (e < DEG) ? nbr_arr[(blk * 4 + tt) * DEG + e]
                                 : nbr_arr[N0C * DEG + blk * 4 + tt];
    }
    __syncthreads();

    {
        const int tl = wave;
        const int gt = blk * 4 + tl;
        int me = (lane <= DEG) ? nbr_s[tl][lane] : 0;
        int k = (lane <= DEG) ? 1 : 0;
#pragma unroll
        for (int j = 0; j < DEG; ++j) {
            int v = __shfl(me, j);
            if (j < lane && v == me) k = 0;
        }
#pragma unroll
        for (int hd = 0; hd < NHEAD; ++hd) {
            float e = s_t[hd * N1C + gt] + s_n[hd * N1C + me];
            e = (e >= 0.f) ? e : ALPHA * e;
            float em = k ? e : -1e30f;
            float m = em;
#pragma unroll
            for (int off = 1; off < 64; off <<= 1) m = fmaxf(m, __shfl_xor(m, off));
            float w = k ? __expf(e - m) : 0.f;
            float Z = w;
#pragma unroll
            for (int off = 1; off < 64; off <<= 1) Z += __shfl_xor(Z, off);
            if (lane <= DEG) att_w[tl][hd][lane] = w / Z;
        }
    }
    __syncthreads();
    {
        const int tl = wave;
        const int hh = lane >> 4;
        float4 acc = make_float4(0.f, 0.f, 0.f, 0.f);
#pragma unroll
        for (int e = 0; e <= DEG; ++e) {
            float w = att_w[tl][hh][e];
            float4 v = ((const float4*)h1)[(size_t)nbr_s[tl][e] * 64 + lane];
            acc.x += w * v.x; acc.y += w * v.y;
            acc.z += w * v.z; acc.w += w * v.w;
        }
        acc.x = (acc.x > 0.f) ? acc.x : expm1f(acc.x);   // ELU
        acc.y = (acc.y > 0.f) ? acc.y : expm1f(acc.y);
        acc.z = (acc.z > 0.f) ? acc.z : expm1f(acc.z);
        acc.w = (acc.w > 0.f) ? acc.w : expm1f(acc.w);
        *(float4*)(&x2[tl][lane * 4]) = acc;
    }
    __syncthreads();

    // final linear: thread = output channel c; fp32 matvec over linW row [c][0..255]
    const int c = threadIdx.x;
    const float4* wrow = (const float4*)(linW + c * 256);
    float v0 = 0.f, v1 = 0.f, v2 = 0.f, v3 = 0.f;
    for (int q = 0; q < 64; ++q) {
        float4 wv = wrow[q];
        int kk = q * 4;
        v0 += x2[0][kk] * wv.x + x2[0][kk+1] * wv.y + x2[0][kk+2] * wv.z + x2[0][kk+3] * wv.w;
        v1 += x2[1][kk] * wv.x + x2[1][kk+1] * wv.y + x2[1][kk+2] * wv.z + x2[1][kk+3] * wv.w;
        v2 += x2[2][kk] * wv.x + x2[2][kk+1] * wv.y + x2[2][kk+2] * wv.z + x2[2][kk+3] * wv.w;
        v3 += x2[3][kk] * wv.x + x2[3][kk+1] * wv.y + x2[3][kk+2] * wv.z + x2[3][kk+3] * wv.w;
    }
    float b = bias[c];
    out[(size_t)(blk * 4 + 0) * 256 + c] = tanhf(v0 + b);
    out[(size_t)(blk * 4 + 1) * 256 + c] = tanhf(v1 + b);
    out[(size_t)(blk * 4 + 2) * 256 + c] = tanhf(v2 + b);
    out[(size_t)(blk * 4 + 3) * 256 + c] = tanhf(v3 + b);
}

extern "C" void kernel_launch(void* const* d_in, const int* in_sizes, int n_in,
                              void* d_out, int out_size, void* d_ws, size_t ws_size,
                              hipStream_t stream)
{
    const float* x    = (const float*)d_in[0];
    const float* W0   = (const float*)d_in[1];
    const float* a0   = (const float*)d_in[2];
    const float* W1   = (const float*)d_in[3];
    const float* a1   = (const float*)d_in[4];
    const float* linW = (const float*)d_in[5];
    const float* linb = (const float*)d_in[6];
    const int* adj1_nbr = (const int*)d_in[8];
    const int* adj0_nbr = (const int*)d_in[10];

    char* base = (char*)d_ws;
    ushort* Wth = (ushort*)base;                 // 2*65536 ushort = 256 KB
    ushort* Wtl = (ushort*)(base + 262144);      // 256 KB          (ends 524288)
    float*  st  = (float*)(base + 524288);       // 4*16000 f32 (256 KB slot)
    float*  sn  = (float*)(base + 786432);       //                 (ends 1048576)
    float*  st2 = (float*)(base + 1048576);      // 4*4000 f32 (64 KB slot)
    float*  sn2 = (float*)(base + 1114112);      //                 (ends 1179648)
    ushort* xhi = (ushort*)(base + 1179648);     // 4000*256 u16 = 2 MB
    ushort* xlo = (ushort*)(base + 3276800);     // 2 MB            (ends 5373952)
    float*  h0  = (float*)(base + 5373952);      // 16000*256 f32 = 16 MB
    float*  h1  = (float*)(base + 21757952);     // 4000*256 f32 = 4 MB (ends ~25.8 MB)

    // K0: weight repack (W0,W1 -> bf16 hi/lo, [n][k]); linW stays fp32
    repack_kernel<<<512, 256, 0, stream>>>(W0, W1, Wth, Wtl);

    // K1: h0 = x @ Wc0 + layer-1 scores
    gemm1_kernel<<<N2C / 32, 256, 0, stream>>>(x, Wth, Wtl, a0, h0, st, sn);

    // K2: att1 (4000 blocks — TLP hides gather latency; round-4 lesson)
    att_kernel<<<N1C, 256, 0, stream>>>(h0, adj1_nbr, st, sn, xhi, xlo, N1C, N2C);

    // K3: gemm2 = x1 @ Wc1 + layer-2 scores
    gemm2_kernel<<<N1C / 16, 256, 0, stream>>>(
        xhi, xlo, Wth + 65536, Wtl + 65536, a1, h1, st2, sn2);

    // K4: att2 -> Linear+Tanh, fused
    att_lin_kernel<<<N0C / 4, 256, 0, stream>>>(
        h1, adj0_nbr, st2, sn2, linW, linb, (float*)d_out);
}